// Round 3
// baseline (937.861 us; speedup 1.0000x reference)
//
#include <hip/hip_runtime.h>
#include <hip/hip_bf16.h>
#include <cstdint>
#include <cmath>

#define B_DIM 8192
#define H_DIM 1024
#define K_DIM 2048   // 2H
#define N_DIM 10240  // 10H

typedef __bf16 bf16x8 __attribute__((ext_vector_type(8)));
typedef float  f32x4  __attribute__((ext_vector_type(4)));

static __device__ __forceinline__ float sigmoid_f(float z) {
    return 1.0f / (1.0f + __expf(-z));
}
static __device__ __forceinline__ float tanh_f(float z) {
    return 1.0f - 2.0f / (1.0f + __expf(2.0f * z));
}
static __device__ __forceinline__ float softplus_f(float z) {
    return fmaxf(z, 0.0f) + log1pf(__expf(-fabsf(z)));
}

static __device__ __forceinline__ void store_bf16x4(__bf16* p, float4 v) {
    alignas(8) __bf16 t[4] = {(__bf16)v.x, (__bf16)v.y, (__bf16)v.z, (__bf16)v.w};
    *reinterpret_cast<uint2*>(p) = *reinterpret_cast<const uint2*>(t);
}

static __device__ __forceinline__ void gload_lds16(const void* g, void* l) {
    auto* gp = reinterpret_cast<__attribute__((address_space(1))) unsigned int*>(
        reinterpret_cast<uintptr_t>(g));
    auto* lp = reinterpret_cast<__attribute__((address_space(3))) unsigned int*>(
        reinterpret_cast<uintptr_t>(l));
    __builtin_amdgcn_global_load_lds(gp, lp, 16, 0, 0);
}

// ---------------- pack kernels (unchanged) ----------------

__global__ void pack_xh_kernel(const float* __restrict__ x, const float* __restrict__ h,
                               __bf16* __restrict__ xh) {
    const int64_t total = (int64_t)B_DIM * K_DIM / 4;
    for (int64_t i = (int64_t)blockIdx.x * blockDim.x + threadIdx.x; i < total;
         i += (int64_t)gridDim.x * blockDim.x) {
        int64_t e = i << 2;
        int64_t b = e >> 11;
        int     c = (int)(e & 2047);
        const float* src = (c < H_DIM) ? (x + b * H_DIM + c) : (h + b * H_DIM + (c - H_DIM));
        float4 v = *reinterpret_cast<const float4*>(src);
        store_bf16x4(xh + e, v);
    }
}

__global__ void pack_W_kernel(const float* __restrict__ w0, const float* __restrict__ w1,
                              const float* __restrict__ w2, const float* __restrict__ w3,
                              const float* __restrict__ w4, const float* __restrict__ w5,
                              const float* __restrict__ wd, __bf16* __restrict__ dst) {
    const int64_t total = (int64_t)N_DIM * K_DIM / 4;
    for (int64_t i = (int64_t)blockIdx.x * blockDim.x + threadIdx.x; i < total;
         i += (int64_t)gridDim.x * blockDim.x) {
        int64_t e   = i << 2;
        int     blk = (int)(e >> 21);
        const float* src;
        int64_t off;
        if (blk < 6) {
            src = (blk == 0) ? w0 : (blk == 1) ? w1 : (blk == 2) ? w2
                : (blk == 3) ? w3 : (blk == 4) ? w4 : w5;
            off = e - ((int64_t)blk << 21);
        } else {
            src = wd;
            off = e - ((int64_t)6 << 21);
        }
        float4 v = *reinterpret_cast<const float4*>(src + off);
        store_bf16x4(dst + e, v);
    }
}

__global__ void pack_bias_kernel(const float* __restrict__ b0, const float* __restrict__ b1,
                                 const float* __restrict__ b2, const float* __restrict__ b3,
                                 const float* __restrict__ b4, const float* __restrict__ b5,
                                 const float* __restrict__ bd, float* __restrict__ dst) {
    int i = blockIdx.x * blockDim.x + threadIdx.x;
    if (i >= N_DIM) return;
    int blk = i >> 10;
    float v;
    if (blk < 6) {
        const float* s = (blk == 0) ? b0 : (blk == 1) ? b1 : (blk == 2) ? b2
                       : (blk == 3) ? b3 : (blk == 4) ? b4 : b5;
        v = s[i - (blk << 10)];
    } else {
        v = bd[i - (6 << 10)];
    }
    dst[i] = v;
}

// ---------------- GEMM: 256x256 tile, BK=64, 8 waves, 8-phase counted-vmcnt ----------------
// Schedule identical to the 517us baseline. This revision changes ONLY the workgroup->tile
// mapping: tn-MAJOR per XCD. Each XCD owns 5 tn columns (5MB of W, fetched once, L2-resident)
// and sweeps all 32 tm rows fast; all 8 XCDs sweep the SAME A panels in tight temporal
// proximity -> A served from die-level L3. Predicted FETCH_SIZE 770MB -> 100-250MB.

#define ACCS(F) \
    F(0,0) F(0,1) F(0,2) F(0,3) F(1,0) F(1,1) F(1,2) F(1,3) \
    F(2,0) F(2,1) F(2,2) F(2,3) F(3,0) F(3,1) F(3,2) F(3,3) \
    F(4,0) F(4,1) F(4,2) F(4,3) F(5,0) F(5,1) F(5,2) F(5,3) \
    F(6,0) F(6,1) F(6,2) F(6,3) F(7,0) F(7,1) F(7,2) F(7,3)

#define MFMA_(A, Bf, C) __builtin_amdgcn_mfma_f32_16x16x32_bf16(A, Bf, C, 0, 0, 0)

#define MR(A0, A1, M) \
    c##M##0 = MFMA_(A0, bb00, c##M##0); c##M##0 = MFMA_(A1, bb01, c##M##0); \
    c##M##1 = MFMA_(A0, bb10, c##M##1); c##M##1 = MFMA_(A1, bb11, c##M##1); \
    c##M##2 = MFMA_(A0, bb20, c##M##2); c##M##2 = MFMA_(A1, bb21, c##M##2); \
    c##M##3 = MFMA_(A0, bb30, c##M##3); c##M##3 = MFMA_(A1, bb31, c##M##3);

#define BARRIER() asm volatile("s_barrier" ::: "memory")
#define LGKM0()   asm volatile("s_waitcnt lgkmcnt(0)" ::: "memory")
#define VMC(N)    asm volatile("s_waitcnt vmcnt(" #N ")" ::: "memory")

#define READ_B(BUF) \
    bb00 = ldB(BUF, 0, 0); bb01 = ldB(BUF, 0, 1); \
    bb10 = ldB(BUF, 1, 0); bb11 = ldB(BUF, 1, 1); \
    bb20 = ldB(BUF, 2, 0); bb21 = ldB(BUF, 2, 1); \
    bb30 = ldB(BUF, 3, 0); bb31 = ldB(BUF, 3, 1);

#define READ_A(BUF, M0, M1) \
    aa0 = ldA(BUF, M0, 0); aa1 = ldA(BUF, M0, 1); \
    aa2 = ldA(BUF, M1, 0); aa3 = ldA(BUF, M1, 1);

#define PHASE_MFMA(ML, MH) \
    __builtin_amdgcn_s_setprio(1); \
    MR(aa0, aa1, ML) MR(aa2, aa3, MH) \
    __builtin_amdgcn_s_setprio(0);

__global__ __launch_bounds__(512, 2) void gemm_fused(
    const __bf16* __restrict__ A,     // [8192][2048]
    const __bf16* __restrict__ W,     // [10240][2048]
    const float* __restrict__ bias,   // [10240]
    float* __restrict__ out,
    __bf16* __restrict__ ggi, __bf16* __restrict__ ggf,
    __bf16* __restrict__ ggib, __bf16* __restrict__ ggfb,
    __bf16* __restrict__ gpc) {
    __shared__ __bf16 As[2 * 16384];
    __shared__ __bf16 Bs[2 * 16384];

    // tn-major per-XCD mapping: xcd = bid&7 owns tn in [xcd*5, xcd*5+5), sweeps tm fast.
    // Concurrent window per XCD ~= one tn column (32 blocks): W panel 1MB hot in its L2;
    // all XCDs read the same tm rows of A concurrently -> L3-served.
    const int bid = blockIdx.x;
    const int xcd = bid & 7;
    const int j   = bid >> 3;          // 0..159 within this XCD's chunk
    const int tm  = j & 31;            // 0..31  (fast: A sweep)
    const int tn  = xcd * 5 + (j >> 5);  // 0..39 (slow: 5 W columns per XCD)

    const int t     = threadIdx.x;
    const int lane  = t & 63;
    const int w     = t >> 6;         // 0..7
    const int wmOff = (w >> 2) << 7;  // 0 or 128
    const int wnOff = (w & 3) << 6;   // 0,64,128,192
    const int lr    = lane & 15;
    const int kg    = lane >> 4;      // 0..3
    const int x7    = lane & 7;
    const int rl    = lane >> 3;      // 0..7 (staging row within wave's 8-row block)
    const int w8    = w << 3;
    const int lane8 = lane << 3;      // element offset = lane*16B
    const int cc8   = ((lane & 7) ^ rl) << 3;  // inverse-swizzled source chunk (elements)

    const int64_t Arow0 = (int64_t)tm * 256;
    const int64_t Wrow0 = (int64_t)tn * 256;

#define DA(M, N) f32x4 c##M##N = {0.f, 0.f, 0.f, 0.f};
    ACCS(DA)
#undef DA
    bf16x8 bb00, bb01, bb10, bb11, bb20, bb21, bb30, bb31;
    bf16x8 aa0, aa1, aa2, aa3;

    // ---- precomputed staging bases (per-lane part once; per-call = literal + uniform koff) ----
    const int wA = ((w >= 4) ? 96 : 0) + w8;  // wave's A-row base (old r0w minus rj*32)
    const __bf16* aSrc = A + (Arow0 + wA + rl) * (int64_t)K_DIM + cc8;
    const __bf16* bSrc = W + (Wrow0 + w8 + rl) * (int64_t)K_DIM + cc8;
    __bf16* ldsA = As + lane8 + wA * 64;
    __bf16* ldsB = Bs + lane8 + w8 * 64;

    auto stageA = [&](int buf, int rj, int koff) {
        gload_lds16(aSrc + rj * (32 * K_DIM) + koff, ldsA + buf * 16384 + rj * 2048);
    };
    auto stageBq = [&](int buf, int q, int koff) {
        gload_lds16(bSrc + q * (64 * K_DIM) + koff, ldsB + buf * 16384 + q * 4096);
    };

    // ---- ds-read bases: swizzle folded in; kh flips exactly bit 6 of the byte offset ----
    const int cLo  = kg ^ (x7 & 3);
    const int b2   = x7 >> 2;  // 0/1
    const int aOff = (wmOff + lr) * 128 + (cLo << 4) + (b2 << 6);
    const int bOff = (wnOff + lr) * 128 + (cLo << 4) + (b2 << 6);
    const char* aRd0 = reinterpret_cast<const char*>(As) + aOff;
    const char* aRd1 = reinterpret_cast<const char*>(As) + (aOff ^ 64);
    const char* bRd0 = reinterpret_cast<const char*>(Bs) + bOff;
    const char* bRd1 = reinterpret_cast<const char*>(Bs) + (bOff ^ 64);

    auto ldA = [&](int buf, int m, int kh) {
        return *reinterpret_cast<const bf16x8*>((kh ? aRd1 : aRd0) + buf * 32768 + m * 2048);
    };
    auto ldB = [&](int buf, int n, int kh) {
        return *reinterpret_cast<const bf16x8*>((kh ? bRd1 : bRd0) + buf * 32768 + n * 2048);
    };

    // ---- prologue: tile0 (8 loads) then tile1 minus A3 (7 loads); vmcnt(7) => tile0 landed ----
    stageA(0, 0, 0); stageA(0, 1, 0); stageA(0, 2, 0); stageA(0, 3, 0);
    stageBq(0, 0, 0); stageBq(0, 1, 0); stageBq(0, 2, 0); stageBq(0, 3, 0);
    stageA(1, 0, 64); stageA(1, 1, 64); stageA(1, 2, 64);
    stageBq(1, 0, 64); stageBq(1, 1, 64); stageBq(1, 2, 64); stageBq(1, 3, 64);
    VMC(7);
    BARRIER();

    // ---- main loop: 16 iterations, 2 K-tiles each (NOT unrolled: keep body inside L1I) ----
#pragma unroll 1
    for (int i = 0; i < 16; ++i) {
        const int k0  = i << 7;              // tile t0=2i element offset
        const int t1o = k0 + 64;
        const int t2o = (k0 + 128) & (K_DIM - 1);
        const int t3o = (k0 + 192) & (K_DIM - 1);

        // P1
        READ_B(0) READ_A(0, 0, 1)
        stageA(1, 3, t1o);
        BARRIER();
        PHASE_MFMA(0, 1)
        LGKM0(); BARRIER();
        // P2
        READ_A(0, 2, 3)
        stageA(0, 0, t2o); stageBq(0, 0, t2o); stageBq(0, 1, t2o);
        BARRIER();
        PHASE_MFMA(2, 3)
        LGKM0(); BARRIER();
        // P3
        READ_A(0, 4, 5)
        stageA(0, 1, t2o); stageBq(0, 2, t2o); stageBq(0, 3, t2o);
        BARRIER();
        PHASE_MFMA(4, 5)
        LGKM0(); BARRIER();
        // P4
        READ_A(0, 6, 7)
        stageA(0, 2, t2o);
        BARRIER();
        PHASE_MFMA(6, 7)
        LGKM0(); VMC(7); BARRIER();
        // P5
        READ_B(1) READ_A(1, 0, 1)
        stageA(0, 3, t2o);
        BARRIER();
        PHASE_MFMA(0, 1)
        LGKM0(); BARRIER();
        // P6
        READ_A(1, 2, 3)
        stageA(1, 0, t3o); stageBq(1, 0, t3o); stageBq(1, 1, t3o);
        BARRIER();
        PHASE_MFMA(2, 3)
        LGKM0(); BARRIER();
        // P7
        READ_A(1, 4, 5)
        stageA(1, 1, t3o); stageBq(1, 2, t3o); stageBq(1, 3, t3o);
        BARRIER();
        PHASE_MFMA(4, 5)
        LGKM0(); BARRIER();
        // P8
        READ_A(1, 6, 7)
        stageA(1, 2, t3o);
        BARRIER();
        PHASE_MFMA(6, 7)
        LGKM0(); VMC(7); BARRIER();
    }
    VMC(0);  // drain wrapped tail stages before exit

    // ---- fused epilogue (bias folded here; loads issued post-loop) ----
    const float bv0 = bias[Wrow0 + wnOff + 0 * 16 + lr];
    const float bv1 = bias[Wrow0 + wnOff + 1 * 16 + lr];
    const float bv2 = bias[Wrow0 + wnOff + 2 * 16 + lr];
    const float bv3 = bias[Wrow0 + wnOff + 3 * 16 + lr];

    const int     blk = tn >> 2;  // 256-col tile fully inside one 1024-col gate block
    const int     lg  = lane >> 4;
    const int64_t BH  = (int64_t)B_DIM * H_DIM;

    auto epi = [&](int m, int n, f32x4 a, float bv) {
        const int64_t rowb = Arow0 + wmOff + m * 16 + lg * 4;
        const int     colo = wnOff + n * 16 + lr;
        if (blk == 2) {  // go -> fp32 output (never re-read: nontemporal)
            float* dst = out + 6 * BH + (Wrow0 - 2 * (int64_t)H_DIM) + colo;
#pragma unroll
            for (int r = 0; r < 4; ++r)
                __builtin_nontemporal_store(sigmoid_f(a[r] + bv), dst + (rowb + r) * H_DIM);
        } else if (blk >= 6) {  // decay -> fp32 output ([B,4H] row-major, never re-read)
            float* dst = out + 2 * BH + (Wrow0 - 6 * (int64_t)H_DIM) + colo;
#pragma unroll
            for (int r = 0; r < 4; ++r)
                __builtin_nontemporal_store(softplus_f(a[r] + bv), dst + (rowb + r) * 4 * H_DIM);
        } else {  // gate -> bf16 workspace (re-read by combine: keep cacheable)
            __bf16* gp = (blk == 0) ? ggi : (blk == 1) ? ggf
                       : (blk == 3) ? ggib : (blk == 4) ? ggfb : gpc;
            __bf16* dst = gp + (int)(Wrow0 & 1023) + colo;
            if (blk == 5) {
#pragma unroll
                for (int r = 0; r < 4; ++r) dst[(rowb + r) * H_DIM] = (__bf16)tanh_f(a[r] + bv);
            } else {
#pragma unroll
                for (int r = 0; r < 4; ++r) dst[(rowb + r) * H_DIM] = (__bf16)sigmoid_f(a[r] + bv);
            }
        }
    };
#define EPI(M, N) epi(M, N, c##M##N, bv##N);
    ACCS(EPI)
#undef EPI
}

// ---------------- combine (cell outputs never re-read: nontemporal stores) ----------------

__global__ void combine_kernel(const __bf16* __restrict__ ggi, const __bf16* __restrict__ ggf,
                               const __bf16* __restrict__ ggib, const __bf16* __restrict__ ggfb,
                               const __bf16* __restrict__ gpc, const float* __restrict__ cp,
                               const float* __restrict__ cbp, float* __restrict__ out) {
    const int64_t BH    = (int64_t)B_DIM * H_DIM;
    const int64_t total = BH / 8;
    for (int64_t i = (int64_t)blockIdx.x * blockDim.x + threadIdx.x; i < total;
         i += (int64_t)gridDim.x * blockDim.x) {
        int64_t e = i << 3;
        bf16x8 vgi  = *reinterpret_cast<const bf16x8*>(ggi + e);
        bf16x8 vgf  = *reinterpret_cast<const bf16x8*>(ggf + e);
        bf16x8 vgib = *reinterpret_cast<const bf16x8*>(ggib + e);
        bf16x8 vgfb = *reinterpret_cast<const bf16x8*>(ggfb + e);
        bf16x8 vpc  = *reinterpret_cast<const bf16x8*>(gpc + e);
        float4 c0  = *reinterpret_cast<const float4*>(cp + e);
        float4 c1  = *reinterpret_cast<const float4*>(cp + e + 4);
        float4 cb0 = *reinterpret_cast<const float4*>(cbp + e);
        float4 cb1 = *reinterpret_cast<const float4*>(cbp + e + 4);
        float cpa[8] = {c0.x, c0.y, c0.z, c0.w, c1.x, c1.y, c1.z, c1.w};
        float cba[8] = {cb0.x, cb0.y, cb0.z, cb0.w, cb1.x, cb1.y, cb1.z, cb1.w};
        float ci[8], cbi[8];
#pragma unroll
        for (int j = 0; j < 8; ++j) {
            float pc = (float)vpc[j];
            ci[j]  = (float)vgf[j]  * cpa[j] + (float)vgi[j]  * pc;
            cbi[j] = (float)vgfb[j] * cba[j] + (float)vgib[j] * pc;
        }
        f32x4 ci0 = {ci[0], ci[1], ci[2], ci[3]};
        f32x4 ci1 = {ci[4], ci[5], ci[6], ci[7]};
        f32x4 cb0v = {cbi[0], cbi[1], cbi[2], cbi[3]};
        f32x4 cb1v = {cbi[4], cbi[5], cbi[6], cbi[7]};
        f32x4* o0 = reinterpret_cast<f32x4*>(out + e);
        __builtin_nontemporal_store(ci0, &o0[0]);
        __builtin_nontemporal_store(ci1, &o0[1]);
        f32x4* o1 = reinterpret_cast<f32x4*>(out + BH + e);
        __builtin_nontemporal_store(cb0v, &o1[0]);
        __builtin_nontemporal_store(cb1v, &o1[1]);
    }
}

// ---------------- launch ----------------

extern "C" void kernel_launch(void* const* d_in, const int* in_sizes, int n_in,
                              void* d_out, int out_size, void* d_ws, size_t ws_size,
                              hipStream_t stream) {
    const float* x   = (const float*)d_in[0];
    const float* h   = (const float*)d_in[1];
    const float* cp  = (const float*)d_in[2];
    const float* cbp = (const float*)d_in[3];
    const float* Wi  = (const float*)d_in[4];
    const float* bi  = (const float*)d_in[5];
    const float* Wf  = (const float*)d_in[6];
    const float* bfo = (const float*)d_in[7];
    const float* Wo  = (const float*)d_in[8];
    const float* bo  = (const float*)d_in[9];
    const float* Wib = (const float*)d_in[10];
    const float* bib = (const float*)d_in[11];
    const float* Wfb = (const float*)d_in[12];
    const float* bfb = (const float*)d_in[13];
    const float* Wpc = (const float*)d_in[14];
    const float* bpc = (const float*)d_in[15];
    const float* Wd  = (const float*)d_in[16];
    const float* bd  = (const float*)d_in[17];
    float* out = (float*)d_out;

    char* ws = (char*)d_ws;
    __bf16* xh   = (__bf16*)ws;
    __bf16* Wb   = (__bf16*)(ws + 33554432);
    float*  bias = (float*)(ws + 75497472);
    __bf16* ggi  = (__bf16*)(ws + 75538432);
    const size_t BH = (size_t)B_DIM * H_DIM;
    __bf16* ggf  = ggi + BH;
    __bf16* ggib = ggf + BH;
    __bf16* ggfb = ggib + BH;
    __bf16* gpc  = ggfb + BH;

    pack_xh_kernel<<<2048, 256, 0, stream>>>(x, h, xh);
    pack_W_kernel<<<2048, 256, 0, stream>>>(Wi, Wf, Wo, Wib, Wfb, Wpc, Wd, Wb);
    pack_bias_kernel<<<40, 256, 0, stream>>>(bi, bfo, bo, bib, bfb, bpc, bd, bias);

    const int grid = (B_DIM / 256) * (N_DIM / 256);  // 1280
    gemm_fused<<<grid, 512, 0, stream>>>(xh, Wb, bias, out, ggi, ggf, ggib, ggfb, gpc);

    combine_kernel<<<4096, 256, 0, stream>>>(ggi, ggf, ggib, ggfb, gpc, cp, cbp, out);
}

// Round 4
// 744.561 us; speedup vs baseline: 1.2596x; 1.2596x over previous
//
#include <hip/hip_runtime.h>
#include <hip/hip_bf16.h>
#include <cstdint>
#include <cmath>

#define B_DIM 8192
#define H_DIM 1024
#define K_DIM 2048   // 2H
#define N_DIM 10240  // 10H

typedef __bf16 bf16x8 __attribute__((ext_vector_type(8)));
typedef float  f32x4  __attribute__((ext_vector_type(4)));

static __device__ __forceinline__ float sigmoid_f(float z) {
    return 1.0f / (1.0f + __expf(-z));
}
static __device__ __forceinline__ float tanh_f(float z) {
    return 1.0f - 2.0f / (1.0f + __expf(2.0f * z));
}
static __device__ __forceinline__ float softplus_f(float z) {
    return fmaxf(z, 0.0f) + log1pf(__expf(-fabsf(z)));
}

static __device__ __forceinline__ void store_bf16x4(__bf16* p, float4 v) {
    alignas(8) __bf16 t[4] = {(__bf16)v.x, (__bf16)v.y, (__bf16)v.z, (__bf16)v.w};
    *reinterpret_cast<uint2*>(p) = *reinterpret_cast<const uint2*>(t);
}

static __device__ __forceinline__ void gload_lds16(const void* g, void* l) {
    auto* gp = reinterpret_cast<__attribute__((address_space(1))) unsigned int*>(
        reinterpret_cast<uintptr_t>(g));
    auto* lp = reinterpret_cast<__attribute__((address_space(3))) unsigned int*>(
        reinterpret_cast<uintptr_t>(l));
    __builtin_amdgcn_global_load_lds(gp, lp, 16, 0, 0);
}

// ---------------- pack kernels (unchanged) ----------------

__global__ void pack_xh_kernel(const float* __restrict__ x, const float* __restrict__ h,
                               __bf16* __restrict__ xh) {
    const int64_t total = (int64_t)B_DIM * K_DIM / 4;
    for (int64_t i = (int64_t)blockIdx.x * blockDim.x + threadIdx.x; i < total;
         i += (int64_t)gridDim.x * blockDim.x) {
        int64_t e = i << 2;
        int64_t b = e >> 11;
        int     c = (int)(e & 2047);
        const float* src = (c < H_DIM) ? (x + b * H_DIM + c) : (h + b * H_DIM + (c - H_DIM));
        float4 v = *reinterpret_cast<const float4*>(src);
        store_bf16x4(xh + e, v);
    }
}

__global__ void pack_W_kernel(const float* __restrict__ w0, const float* __restrict__ w1,
                              const float* __restrict__ w2, const float* __restrict__ w3,
                              const float* __restrict__ w4, const float* __restrict__ w5,
                              const float* __restrict__ wd, __bf16* __restrict__ dst) {
    const int64_t total = (int64_t)N_DIM * K_DIM / 4;
    for (int64_t i = (int64_t)blockIdx.x * blockDim.x + threadIdx.x; i < total;
         i += (int64_t)gridDim.x * blockDim.x) {
        int64_t e   = i << 2;
        int     blk = (int)(e >> 21);
        const float* src;
        int64_t off;
        if (blk < 6) {
            src = (blk == 0) ? w0 : (blk == 1) ? w1 : (blk == 2) ? w2
                : (blk == 3) ? w3 : (blk == 4) ? w4 : w5;
            off = e - ((int64_t)blk << 21);
        } else {
            src = wd;
            off = e - ((int64_t)6 << 21);
        }
        float4 v = *reinterpret_cast<const float4*>(src + off);
        store_bf16x4(dst + e, v);
    }
}

__global__ void pack_bias_kernel(const float* __restrict__ b0, const float* __restrict__ b1,
                                 const float* __restrict__ b2, const float* __restrict__ b3,
                                 const float* __restrict__ b4, const float* __restrict__ b5,
                                 const float* __restrict__ bd, float* __restrict__ dst) {
    int i = blockIdx.x * blockDim.x + threadIdx.x;
    if (i >= N_DIM) return;
    int blk = i >> 10;
    float v;
    if (blk < 6) {
        const float* s = (blk == 0) ? b0 : (blk == 1) ? b1 : (blk == 2) ? b2
                       : (blk == 3) ? b3 : (blk == 4) ? b4 : b5;
        v = s[i - (blk << 10)];
    } else {
        v = bd[i - (6 << 10)];
    }
    dst[i] = v;
}

// ---------------- GEMM: 256x256 tile, BK=64, 8 waves, 8-phase counted-vmcnt ----------------
// Identical to the round-2 (685us) kernel except the workgroup->tile mapping:
// r2 mapping (tm = 4*xcd + j/40, tn = j%40) kept the per-XCD A panel L2-resident but made
// ALL 8 XCDs sweep the SAME tn sequence in lockstep -> same-instant same-address W misses
// (L3 slice hotspot / duplicated HBM fetches; FETCH=770MB vs 75MB compulsory).
// Fix: rotate each XCD's tn start by 5: tn = (j%40 + 5*xcd) % 40. Disjoint concurrent W
// panels; W lines fetched once into L3 and L3-hit by the other XCDs later. Bijective.

#define ACCS(F) \
    F(0,0) F(0,1) F(0,2) F(0,3) F(1,0) F(1,1) F(1,2) F(1,3) \
    F(2,0) F(2,1) F(2,2) F(2,3) F(3,0) F(3,1) F(3,2) F(3,3) \
    F(4,0) F(4,1) F(4,2) F(4,3) F(5,0) F(5,1) F(5,2) F(5,3) \
    F(6,0) F(6,1) F(6,2) F(6,3) F(7,0) F(7,1) F(7,2) F(7,3)

#define MFMA_(A, Bf, C) __builtin_amdgcn_mfma_f32_16x16x32_bf16(A, Bf, C, 0, 0, 0)

#define MR(A0, A1, M) \
    c##M##0 = MFMA_(A0, bb00, c##M##0); c##M##0 = MFMA_(A1, bb01, c##M##0); \
    c##M##1 = MFMA_(A0, bb10, c##M##1); c##M##1 = MFMA_(A1, bb11, c##M##1); \
    c##M##2 = MFMA_(A0, bb20, c##M##2); c##M##2 = MFMA_(A1, bb21, c##M##2); \
    c##M##3 = MFMA_(A0, bb30, c##M##3); c##M##3 = MFMA_(A1, bb31, c##M##3);

#define BARRIER() asm volatile("s_barrier" ::: "memory")
#define LGKM0()   asm volatile("s_waitcnt lgkmcnt(0)" ::: "memory")
#define VMC(N)    asm volatile("s_waitcnt vmcnt(" #N ")" ::: "memory")

#define READ_B(BUF) \
    bb00 = ldB(BUF, 0, 0); bb01 = ldB(BUF, 0, 1); \
    bb10 = ldB(BUF, 1, 0); bb11 = ldB(BUF, 1, 1); \
    bb20 = ldB(BUF, 2, 0); bb21 = ldB(BUF, 2, 1); \
    bb30 = ldB(BUF, 3, 0); bb31 = ldB(BUF, 3, 1);

#define READ_A(BUF, M0, M1) \
    aa0 = ldA(BUF, M0, 0); aa1 = ldA(BUF, M0, 1); \
    aa2 = ldA(BUF, M1, 0); aa3 = ldA(BUF, M1, 1);

#define PHASE_MFMA(ML, MH) \
    __builtin_amdgcn_s_setprio(1); \
    MR(aa0, aa1, ML) MR(aa2, aa3, MH) \
    __builtin_amdgcn_s_setprio(0);

__global__ __launch_bounds__(512, 2) void gemm_fused(
    const __bf16* __restrict__ A,     // [8192][2048]
    const __bf16* __restrict__ W,     // [10240][2048]
    const float* __restrict__ bias,   // [10240]
    float* __restrict__ out,
    __bf16* __restrict__ ggi, __bf16* __restrict__ ggf,
    __bf16* __restrict__ ggib, __bf16* __restrict__ ggfb,
    __bf16* __restrict__ gpc) {
    __shared__ __bf16 As[2 * 16384];
    __shared__ __bf16 Bs[2 * 16384];

    // r2 mapping + per-XCD tn rotation (desynchronize cross-XCD W streams).
    const int bid = blockIdx.x;
    const int xcd = bid & 7;
    const int j   = bid >> 3;            // 0..159 within this XCD's sequence
    const int jm  = j % 40;
    const int tm  = xcd * 4 + j / 40;    // 4-row A band per XCD (A panel L2-resident)
    int       tn  = jm + 5 * xcd;        // rotated start: disjoint concurrent W panels
    if (tn >= 40) tn -= 40;

    const int t     = threadIdx.x;
    const int lane  = t & 63;
    const int w     = t >> 6;         // 0..7
    const int wmOff = (w >> 2) << 7;  // 0 or 128
    const int wnOff = (w & 3) << 6;   // 0,64,128,192
    const int lr    = lane & 15;
    const int kg    = lane >> 4;      // 0..3
    const int x7    = lane & 7;
    const int rl    = lane >> 3;      // 0..7 (staging row within wave's 8-row block)
    const int w8    = w << 3;
    const int lane8 = lane << 3;      // element offset = lane*16B
    const int cc8   = ((lane & 7) ^ rl) << 3;  // inverse-swizzled source chunk (elements)

    const int64_t Arow0 = (int64_t)tm * 256;
    const int64_t Wrow0 = (int64_t)tn * 256;

#define DA(M, N) f32x4 c##M##N = {0.f, 0.f, 0.f, 0.f};
    ACCS(DA)
#undef DA
    bf16x8 bb00, bb01, bb10, bb11, bb20, bb21, bb30, bb31;
    bf16x8 aa0, aa1, aa2, aa3;

    // ---- precomputed staging bases (per-lane part once; per-call = literal + uniform koff) ----
    const int wA = ((w >= 4) ? 96 : 0) + w8;  // wave's A-row base (old r0w minus rj*32)
    const __bf16* aSrc = A + (Arow0 + wA + rl) * (int64_t)K_DIM + cc8;
    const __bf16* bSrc = W + (Wrow0 + w8 + rl) * (int64_t)K_DIM + cc8;
    __bf16* ldsA = As + lane8 + wA * 64;
    __bf16* ldsB = Bs + lane8 + w8 * 64;

    auto stageA = [&](int buf, int rj, int koff) {
        gload_lds16(aSrc + rj * (32 * K_DIM) + koff, ldsA + buf * 16384 + rj * 2048);
    };
    auto stageBq = [&](int buf, int q, int koff) {
        gload_lds16(bSrc + q * (64 * K_DIM) + koff, ldsB + buf * 16384 + q * 4096);
    };

    // ---- ds-read bases: swizzle folded in; kh flips exactly bit 6 of the byte offset ----
    const int cLo  = kg ^ (x7 & 3);
    const int b2   = x7 >> 2;  // 0/1
    const int aOff = (wmOff + lr) * 128 + (cLo << 4) + (b2 << 6);
    const int bOff = (wnOff + lr) * 128 + (cLo << 4) + (b2 << 6);
    const char* aRd0 = reinterpret_cast<const char*>(As) + aOff;
    const char* aRd1 = reinterpret_cast<const char*>(As) + (aOff ^ 64);
    const char* bRd0 = reinterpret_cast<const char*>(Bs) + bOff;
    const char* bRd1 = reinterpret_cast<const char*>(Bs) + (bOff ^ 64);

    auto ldA = [&](int buf, int m, int kh) {
        return *reinterpret_cast<const bf16x8*>((kh ? aRd1 : aRd0) + buf * 32768 + m * 2048);
    };
    auto ldB = [&](int buf, int n, int kh) {
        return *reinterpret_cast<const bf16x8*>((kh ? bRd1 : bRd0) + buf * 32768 + n * 2048);
    };

    // ---- prologue: tile0 (8 loads) then tile1 minus A3 (7 loads); vmcnt(7) => tile0 landed ----
    stageA(0, 0, 0); stageA(0, 1, 0); stageA(0, 2, 0); stageA(0, 3, 0);
    stageBq(0, 0, 0); stageBq(0, 1, 0); stageBq(0, 2, 0); stageBq(0, 3, 0);
    stageA(1, 0, 64); stageA(1, 1, 64); stageA(1, 2, 64);
    stageBq(1, 0, 64); stageBq(1, 1, 64); stageBq(1, 2, 64); stageBq(1, 3, 64);
    VMC(7);
    BARRIER();

    // ---- main loop: 16 iterations, 2 K-tiles each (NOT unrolled: keep body inside L1I) ----
#pragma unroll 1
    for (int i = 0; i < 16; ++i) {
        const int k0  = i << 7;              // tile t0=2i element offset
        const int t1o = k0 + 64;
        const int t2o = (k0 + 128) & (K_DIM - 1);
        const int t3o = (k0 + 192) & (K_DIM - 1);

        // P1
        READ_B(0) READ_A(0, 0, 1)
        stageA(1, 3, t1o);
        BARRIER();
        PHASE_MFMA(0, 1)
        LGKM0(); BARRIER();
        // P2
        READ_A(0, 2, 3)
        stageA(0, 0, t2o); stageBq(0, 0, t2o); stageBq(0, 1, t2o);
        BARRIER();
        PHASE_MFMA(2, 3)
        LGKM0(); BARRIER();
        // P3
        READ_A(0, 4, 5)
        stageA(0, 1, t2o); stageBq(0, 2, t2o); stageBq(0, 3, t2o);
        BARRIER();
        PHASE_MFMA(4, 5)
        LGKM0(); BARRIER();
        // P4
        READ_A(0, 6, 7)
        stageA(0, 2, t2o);
        BARRIER();
        PHASE_MFMA(6, 7)
        LGKM0(); VMC(7); BARRIER();
        // P5
        READ_B(1) READ_A(1, 0, 1)
        stageA(0, 3, t2o);
        BARRIER();
        PHASE_MFMA(0, 1)
        LGKM0(); BARRIER();
        // P6
        READ_A(1, 2, 3)
        stageA(1, 0, t3o); stageBq(1, 0, t3o); stageBq(1, 1, t3o);
        BARRIER();
        PHASE_MFMA(2, 3)
        LGKM0(); BARRIER();
        // P7
        READ_A(1, 4, 5)
        stageA(1, 1, t3o); stageBq(1, 2, t3o); stageBq(1, 3, t3o);
        BARRIER();
        PHASE_MFMA(4, 5)
        LGKM0(); BARRIER();
        // P8
        READ_A(1, 6, 7)
        stageA(1, 2, t3o);
        BARRIER();
        PHASE_MFMA(6, 7)
        LGKM0(); VMC(7); BARRIER();
    }
    VMC(0);  // drain wrapped tail stages before exit

    // ---- fused epilogue (bias folded here; loads issued post-loop) ----
    const float bv0 = bias[Wrow0 + wnOff + 0 * 16 + lr];
    const float bv1 = bias[Wrow0 + wnOff + 1 * 16 + lr];
    const float bv2 = bias[Wrow0 + wnOff + 2 * 16 + lr];
    const float bv3 = bias[Wrow0 + wnOff + 3 * 16 + lr];

    const int     blk = tn >> 2;  // 256-col tile fully inside one 1024-col gate block
    const int     lg  = lane >> 4;
    const int64_t BH  = (int64_t)B_DIM * H_DIM;

    auto epi = [&](int m, int n, f32x4 a, float bv) {
        const int64_t rowb = Arow0 + wmOff + m * 16 + lg * 4;
        const int     colo = wnOff + n * 16 + lr;
        if (blk == 2) {  // go -> fp32 output (never re-read: nontemporal)
            float* dst = out + 6 * BH + (Wrow0 - 2 * (int64_t)H_DIM) + colo;
#pragma unroll
            for (int r = 0; r < 4; ++r)
                __builtin_nontemporal_store(sigmoid_f(a[r] + bv), dst + (rowb + r) * H_DIM);
        } else if (blk >= 6) {  // decay -> fp32 output ([B,4H] row-major, never re-read)
            float* dst = out + 2 * BH + (Wrow0 - 6 * (int64_t)H_DIM) + colo;
#pragma unroll
            for (int r = 0; r < 4; ++r)
                __builtin_nontemporal_store(softplus_f(a[r] + bv), dst + (rowb + r) * 4 * H_DIM);
        } else {  // gate -> bf16 workspace (re-read by combine: keep cacheable)
            __bf16* gp = (blk == 0) ? ggi : (blk == 1) ? ggf
                       : (blk == 3) ? ggib : (blk == 4) ? ggfb : gpc;
            __bf16* dst = gp + (int)(Wrow0 & 1023) + colo;
            if (blk == 5) {
#pragma unroll
                for (int r = 0; r < 4; ++r) dst[(rowb + r) * H_DIM] = (__bf16)tanh_f(a[r] + bv);
            } else {
#pragma unroll
                for (int r = 0; r < 4; ++r) dst[(rowb + r) * H_DIM] = (__bf16)sigmoid_f(a[r] + bv);
            }
        }
    };
#define EPI(M, N) epi(M, N, c##M##N, bv##N);
    ACCS(EPI)
#undef EPI
}

// ---------------- combine (cell outputs never re-read: nontemporal stores) ----------------

__global__ void combine_kernel(const __bf16* __restrict__ ggi, const __bf16* __restrict__ ggf,
                               const __bf16* __restrict__ ggib, const __bf16* __restrict__ ggfb,
                               const __bf16* __restrict__ gpc, const float* __restrict__ cp,
                               const float* __restrict__ cbp, float* __restrict__ out) {
    const int64_t BH    = (int64_t)B_DIM * H_DIM;
    const int64_t total = BH / 8;
    for (int64_t i = (int64_t)blockIdx.x * blockDim.x + threadIdx.x; i < total;
         i += (int64_t)gridDim.x * blockDim.x) {
        int64_t e = i << 3;
        bf16x8 vgi  = *reinterpret_cast<const bf16x8*>(ggi + e);
        bf16x8 vgf  = *reinterpret_cast<const bf16x8*>(ggf + e);
        bf16x8 vgib = *reinterpret_cast<const bf16x8*>(ggib + e);
        bf16x8 vgfb = *reinterpret_cast<const bf16x8*>(ggfb + e);
        bf16x8 vpc  = *reinterpret_cast<const bf16x8*>(gpc + e);
        float4 c0  = *reinterpret_cast<const float4*>(cp + e);
        float4 c1  = *reinterpret_cast<const float4*>(cp + e + 4);
        float4 cb0 = *reinterpret_cast<const float4*>(cbp + e);
        float4 cb1 = *reinterpret_cast<const float4*>(cbp + e + 4);
        float cpa[8] = {c0.x, c0.y, c0.z, c0.w, c1.x, c1.y, c1.z, c1.w};
        float cba[8] = {cb0.x, cb0.y, cb0.z, cb0.w, cb1.x, cb1.y, cb1.z, cb1.w};
        float ci[8], cbi[8];
#pragma unroll
        for (int j = 0; j < 8; ++j) {
            float pc = (float)vpc[j];
            ci[j]  = (float)vgf[j]  * cpa[j] + (float)vgi[j]  * pc;
            cbi[j] = (float)vgfb[j] * cba[j] + (float)vgib[j] * pc;
        }
        f32x4 ci0 = {ci[0], ci[1], ci[2], ci[3]};
        f32x4 ci1 = {ci[4], ci[5], ci[6], ci[7]};
        f32x4 cb0v = {cbi[0], cbi[1], cbi[2], cbi[3]};
        f32x4 cb1v = {cbi[4], cbi[5], cbi[6], cbi[7]};
        f32x4* o0 = reinterpret_cast<f32x4*>(out + e);
        __builtin_nontemporal_store(ci0, &o0[0]);
        __builtin_nontemporal_store(ci1, &o0[1]);
        f32x4* o1 = reinterpret_cast<f32x4*>(out + BH + e);
        __builtin_nontemporal_store(cb0v, &o1[0]);
        __builtin_nontemporal_store(cb1v, &o1[1]);
    }
}

// ---------------- launch ----------------

extern "C" void kernel_launch(void* const* d_in, const int* in_sizes, int n_in,
                              void* d_out, int out_size, void* d_ws, size_t ws_size,
                              hipStream_t stream) {
    const float* x   = (const float*)d_in[0];
    const float* h   = (const float*)d_in[1];
    const float* cp  = (const float*)d_in[2];
    const float* cbp = (const float*)d_in[3];
    const float* Wi  = (const float*)d_in[4];
    const float* bi  = (const float*)d_in[5];
    const float* Wf  = (const float*)d_in[6];
    const float* bfo = (const float*)d_in[7];
    const float* Wo  = (const float*)d_in[8];
    const float* bo  = (const float*)d_in[9];
    const float* Wib = (const float*)d_in[10];
    const float* bib = (const float*)d_in[11];
    const float* Wfb = (const float*)d_in[12];
    const float* bfb = (const float*)d_in[13];
    const float* Wpc = (const float*)d_in[14];
    const float* bpc = (const float*)d_in[15];
    const float* Wd  = (const float*)d_in[16];
    const float* bd  = (const float*)d_in[17];
    float* out = (float*)d_out;

    char* ws = (char*)d_ws;
    __bf16* xh   = (__bf16*)ws;
    __bf16* Wb   = (__bf16*)(ws + 33554432);
    float*  bias = (float*)(ws + 75497472);
    __bf16* ggi  = (__bf16*)(ws + 75538432);
    const size_t BH = (size_t)B_DIM * H_DIM;
    __bf16* ggf  = ggi + BH;
    __bf16* ggib = ggf + BH;
    __bf16* ggfb = ggib + BH;
    __bf16* gpc  = ggfb + BH;

    pack_xh_kernel<<<2048, 256, 0, stream>>>(x, h, xh);
    pack_W_kernel<<<2048, 256, 0, stream>>>(Wi, Wf, Wo, Wib, Wfb, Wpc, Wd, Wb);
    pack_bias_kernel<<<40, 256, 0, stream>>>(bi, bfo, bo, bib, bfb, bpc, bd, bias);

    const int grid = (B_DIM / 256) * (N_DIM / 256);  // 1280
    gemm_fused<<<grid, 512, 0, stream>>>(xh, Wb, bias, out, ggi, ggf, ggib, ggfb, gpc);

    combine_kernel<<<4096, 256, 0, stream>>>(ggi, ggf, ggib, ggfb, gpc, cp, cbp, out);
}

// Round 5
// 731.999 us; speedup vs baseline: 1.2812x; 1.0172x over previous
//
#include <hip/hip_runtime.h>
#include <hip/hip_bf16.h>
#include <cstdint>
#include <cmath>

#define B_DIM 8192
#define H_DIM 1024
#define K_DIM 2048   // 2H
#define N_DIM 10240  // 10H

typedef __bf16 bf16x8 __attribute__((ext_vector_type(8)));
typedef float  f32x4  __attribute__((ext_vector_type(4)));

static __device__ __forceinline__ float sigmoid_f(float z) {
    return 1.0f / (1.0f + __expf(-z));
}
static __device__ __forceinline__ float tanh_f(float z) {
    return 1.0f - 2.0f / (1.0f + __expf(2.0f * z));
}
static __device__ __forceinline__ float softplus_f(float z) {
    return fmaxf(z, 0.0f) + log1pf(__expf(-fabsf(z)));
}

static __device__ __forceinline__ void store_bf16x4(__bf16* p, float4 v) {
    alignas(8) __bf16 t[4] = {(__bf16)v.x, (__bf16)v.y, (__bf16)v.z, (__bf16)v.w};
    *reinterpret_cast<uint2*>(p) = *reinterpret_cast<const uint2*>(t);
}

static __device__ __forceinline__ void gload_lds16(const void* g, void* l) {
    auto* gp = reinterpret_cast<__attribute__((address_space(1))) unsigned int*>(
        reinterpret_cast<uintptr_t>(g));
    auto* lp = reinterpret_cast<__attribute__((address_space(3))) unsigned int*>(
        reinterpret_cast<uintptr_t>(l));
    __builtin_amdgcn_global_load_lds(gp, lp, 16, 0, 0);
}

// ---------------- pack kernels (unchanged) ----------------

__global__ void pack_xh_kernel(const float* __restrict__ x, const float* __restrict__ h,
                               __bf16* __restrict__ xh) {
    const int64_t total = (int64_t)B_DIM * K_DIM / 4;
    for (int64_t i = (int64_t)blockIdx.x * blockDim.x + threadIdx.x; i < total;
         i += (int64_t)gridDim.x * blockDim.x) {
        int64_t e = i << 2;
        int64_t b = e >> 11;
        int     c = (int)(e & 2047);
        const float* src = (c < H_DIM) ? (x + b * H_DIM + c) : (h + b * H_DIM + (c - H_DIM));
        float4 v = *reinterpret_cast<const float4*>(src);
        store_bf16x4(xh + e, v);
    }
}

__global__ void pack_W_kernel(const float* __restrict__ w0, const float* __restrict__ w1,
                              const float* __restrict__ w2, const float* __restrict__ w3,
                              const float* __restrict__ w4, const float* __restrict__ w5,
                              const float* __restrict__ wd, __bf16* __restrict__ dst) {
    const int64_t total = (int64_t)N_DIM * K_DIM / 4;
    for (int64_t i = (int64_t)blockIdx.x * blockDim.x + threadIdx.x; i < total;
         i += (int64_t)gridDim.x * blockDim.x) {
        int64_t e   = i << 2;
        int     blk = (int)(e >> 21);
        const float* src;
        int64_t off;
        if (blk < 6) {
            src = (blk == 0) ? w0 : (blk == 1) ? w1 : (blk == 2) ? w2
                : (blk == 3) ? w3 : (blk == 4) ? w4 : w5;
            off = e - ((int64_t)blk << 21);
        } else {
            src = wd;
            off = e - ((int64_t)6 << 21);
        }
        float4 v = *reinterpret_cast<const float4*>(src + off);
        store_bf16x4(dst + e, v);
    }
}

__global__ void pack_bias_kernel(const float* __restrict__ b0, const float* __restrict__ b1,
                                 const float* __restrict__ b2, const float* __restrict__ b3,
                                 const float* __restrict__ b4, const float* __restrict__ b5,
                                 const float* __restrict__ bd, float* __restrict__ dst) {
    int i = blockIdx.x * blockDim.x + threadIdx.x;
    if (i >= N_DIM) return;
    int blk = i >> 10;
    float v;
    if (blk < 6) {
        const float* s = (blk == 0) ? b0 : (blk == 1) ? b1 : (blk == 2) ? b2
                       : (blk == 3) ? b3 : (blk == 4) ? b4 : b5;
        v = s[i - (blk << 10)];
    } else {
        v = bd[i - (6 << 10)];
    }
    dst[i] = v;
}

// ---------------- GEMM: 256x256 tile, BK=64, 8 waves, 8-phase counted-vmcnt ----------------
// Identical to the round-2 (best, 685us) kernel except the workgroup->tile mapping:
// 2D-chunked per-XCD order. XCD k keeps its tm band [4k,4k+4) (r2 property) but sweeps tn in
// OCTETS: 32-block sub-squares of 4 tm x 8 tn == exactly the XCD's concurrent capacity.
// Concurrent working set/XCD: A 4MB + W 8MB; K-slice window under drift ~2MB < 4MB L2 ->
// staging becomes L2-hit. All XCDs sweep the same octets in lockstep (keeps r2's good
// cross-XCD same-address property that r4's rotation broke). W fetched once per XCD.

#define ACCS(F) \
    F(0,0) F(0,1) F(0,2) F(0,3) F(1,0) F(1,1) F(1,2) F(1,3) \
    F(2,0) F(2,1) F(2,2) F(2,3) F(3,0) F(3,1) F(3,2) F(3,3) \
    F(4,0) F(4,1) F(4,2) F(4,3) F(5,0) F(5,1) F(5,2) F(5,3) \
    F(6,0) F(6,1) F(6,2) F(6,3) F(7,0) F(7,1) F(7,2) F(7,3)

#define MFMA_(A, Bf, C) __builtin_amdgcn_mfma_f32_16x16x32_bf16(A, Bf, C, 0, 0, 0)

#define MR(A0, A1, M) \
    c##M##0 = MFMA_(A0, bb00, c##M##0); c##M##0 = MFMA_(A1, bb01, c##M##0); \
    c##M##1 = MFMA_(A0, bb10, c##M##1); c##M##1 = MFMA_(A1, bb11, c##M##1); \
    c##M##2 = MFMA_(A0, bb20, c##M##2); c##M##2 = MFMA_(A1, bb21, c##M##2); \
    c##M##3 = MFMA_(A0, bb30, c##M##3); c##M##3 = MFMA_(A1, bb31, c##M##3);

#define BARRIER() asm volatile("s_barrier" ::: "memory")
#define LGKM0()   asm volatile("s_waitcnt lgkmcnt(0)" ::: "memory")
#define VMC(N)    asm volatile("s_waitcnt vmcnt(" #N ")" ::: "memory")

#define READ_B(BUF) \
    bb00 = ldB(BUF, 0, 0); bb01 = ldB(BUF, 0, 1); \
    bb10 = ldB(BUF, 1, 0); bb11 = ldB(BUF, 1, 1); \
    bb20 = ldB(BUF, 2, 0); bb21 = ldB(BUF, 2, 1); \
    bb30 = ldB(BUF, 3, 0); bb31 = ldB(BUF, 3, 1);

#define READ_A(BUF, M0, M1) \
    aa0 = ldA(BUF, M0, 0); aa1 = ldA(BUF, M0, 1); \
    aa2 = ldA(BUF, M1, 0); aa3 = ldA(BUF, M1, 1);

#define PHASE_MFMA(ML, MH) \
    __builtin_amdgcn_s_setprio(1); \
    MR(aa0, aa1, ML) MR(aa2, aa3, MH) \
    __builtin_amdgcn_s_setprio(0);

__global__ __launch_bounds__(512, 2) void gemm_fused(
    const __bf16* __restrict__ A,     // [8192][2048]
    const __bf16* __restrict__ W,     // [10240][2048]
    const float* __restrict__ bias,   // [10240]
    float* __restrict__ out,
    __bf16* __restrict__ ggi, __bf16* __restrict__ ggf,
    __bf16* __restrict__ ggib, __bf16* __restrict__ ggfb,
    __bf16* __restrict__ gpc) {
    __shared__ __bf16 As[2 * 16384];
    __shared__ __bf16 Bs[2 * 16384];

    // 2D-chunked per-XCD mapping: tm band per XCD, tn swept in octets of 8.
    const int bid = blockIdx.x;
    const int xcd = bid & 7;
    const int j   = bid >> 3;            // 0..159 within this XCD's sequence
    const int oct = j >> 5;              // 0..4   (tn octet; same across XCDs at same time)
    const int jj  = j & 31;              // 0..31  (position inside 4x8 sub-square)
    const int tm  = xcd * 4 + (jj >> 3); // 4-row A band per XCD (A 4MB, L2-resident)
    const int tn  = oct * 8 + (jj & 7);  // 8-col W octet (W 8MB concurrent, K-slice L2-fit)

    const int t     = threadIdx.x;
    const int lane  = t & 63;
    const int w     = t >> 6;         // 0..7
    const int wmOff = (w >> 2) << 7;  // 0 or 128
    const int wnOff = (w & 3) << 6;   // 0,64,128,192
    const int lr    = lane & 15;
    const int kg    = lane >> 4;      // 0..3
    const int x7    = lane & 7;
    const int rl    = lane >> 3;      // 0..7 (staging row within wave's 8-row block)
    const int w8    = w << 3;
    const int lane8 = lane << 3;      // element offset = lane*16B
    const int cc8   = ((lane & 7) ^ rl) << 3;  // inverse-swizzled source chunk (elements)

    const int64_t Arow0 = (int64_t)tm * 256;
    const int64_t Wrow0 = (int64_t)tn * 256;

#define DA(M, N) f32x4 c##M##N = {0.f, 0.f, 0.f, 0.f};
    ACCS(DA)
#undef DA
    bf16x8 bb00, bb01, bb10, bb11, bb20, bb21, bb30, bb31;
    bf16x8 aa0, aa1, aa2, aa3;

    // ---- precomputed staging bases (per-lane part once; per-call = literal + uniform koff) ----
    const int wA = ((w >= 4) ? 96 : 0) + w8;  // wave's A-row base (old r0w minus rj*32)
    const __bf16* aSrc = A + (Arow0 + wA + rl) * (int64_t)K_DIM + cc8;
    const __bf16* bSrc = W + (Wrow0 + w8 + rl) * (int64_t)K_DIM + cc8;
    __bf16* ldsA = As + lane8 + wA * 64;
    __bf16* ldsB = Bs + lane8 + w8 * 64;

    auto stageA = [&](int buf, int rj, int koff) {
        gload_lds16(aSrc + rj * (32 * K_DIM) + koff, ldsA + buf * 16384 + rj * 2048);
    };
    auto stageBq = [&](int buf, int q, int koff) {
        gload_lds16(bSrc + q * (64 * K_DIM) + koff, ldsB + buf * 16384 + q * 4096);
    };

    // ---- ds-read bases: swizzle folded in; kh flips exactly bit 6 of the byte offset ----
    const int cLo  = kg ^ (x7 & 3);
    const int b2   = x7 >> 2;  // 0/1
    const int aOff = (wmOff + lr) * 128 + (cLo << 4) + (b2 << 6);
    const int bOff = (wnOff + lr) * 128 + (cLo << 4) + (b2 << 6);
    const char* aRd0 = reinterpret_cast<const char*>(As) + aOff;
    const char* aRd1 = reinterpret_cast<const char*>(As) + (aOff ^ 64);
    const char* bRd0 = reinterpret_cast<const char*>(Bs) + bOff;
    const char* bRd1 = reinterpret_cast<const char*>(Bs) + (bOff ^ 64);

    auto ldA = [&](int buf, int m, int kh) {
        return *reinterpret_cast<const bf16x8*>((kh ? aRd1 : aRd0) + buf * 32768 + m * 2048);
    };
    auto ldB = [&](int buf, int n, int kh) {
        return *reinterpret_cast<const bf16x8*>((kh ? bRd1 : bRd0) + buf * 32768 + n * 2048);
    };

    // ---- prologue: tile0 (8 loads) then tile1 minus A3 (7 loads); vmcnt(7) => tile0 landed ----
    stageA(0, 0, 0); stageA(0, 1, 0); stageA(0, 2, 0); stageA(0, 3, 0);
    stageBq(0, 0, 0); stageBq(0, 1, 0); stageBq(0, 2, 0); stageBq(0, 3, 0);
    stageA(1, 0, 64); stageA(1, 1, 64); stageA(1, 2, 64);
    stageBq(1, 0, 64); stageBq(1, 1, 64); stageBq(1, 2, 64); stageBq(1, 3, 64);
    VMC(7);
    BARRIER();

    // ---- main loop: 16 iterations, 2 K-tiles each (NOT unrolled: keep body inside L1I) ----
#pragma unroll 1
    for (int i = 0; i < 16; ++i) {
        const int k0  = i << 7;              // tile t0=2i element offset
        const int t1o = k0 + 64;
        const int t2o = (k0 + 128) & (K_DIM - 1);
        const int t3o = (k0 + 192) & (K_DIM - 1);

        // P1
        READ_B(0) READ_A(0, 0, 1)
        stageA(1, 3, t1o);
        BARRIER();
        PHASE_MFMA(0, 1)
        LGKM0(); BARRIER();
        // P2
        READ_A(0, 2, 3)
        stageA(0, 0, t2o); stageBq(0, 0, t2o); stageBq(0, 1, t2o);
        BARRIER();
        PHASE_MFMA(2, 3)
        LGKM0(); BARRIER();
        // P3
        READ_A(0, 4, 5)
        stageA(0, 1, t2o); stageBq(0, 2, t2o); stageBq(0, 3, t2o);
        BARRIER();
        PHASE_MFMA(4, 5)
        LGKM0(); BARRIER();
        // P4
        READ_A(0, 6, 7)
        stageA(0, 2, t2o);
        BARRIER();
        PHASE_MFMA(6, 7)
        LGKM0(); VMC(7); BARRIER();
        // P5
        READ_B(1) READ_A(1, 0, 1)
        stageA(0, 3, t2o);
        BARRIER();
        PHASE_MFMA(0, 1)
        LGKM0(); BARRIER();
        // P6
        READ_A(1, 2, 3)
        stageA(1, 0, t3o); stageBq(1, 0, t3o); stageBq(1, 1, t3o);
        BARRIER();
        PHASE_MFMA(2, 3)
        LGKM0(); BARRIER();
        // P7
        READ_A(1, 4, 5)
        stageA(1, 1, t3o); stageBq(1, 2, t3o); stageBq(1, 3, t3o);
        BARRIER();
        PHASE_MFMA(4, 5)
        LGKM0(); BARRIER();
        // P8
        READ_A(1, 6, 7)
        stageA(1, 2, t3o);
        BARRIER();
        PHASE_MFMA(6, 7)
        LGKM0(); VMC(7); BARRIER();
    }
    VMC(0);  // drain wrapped tail stages before exit

    // ---- fused epilogue (bias folded here; loads issued post-loop) ----
    const float bv0 = bias[Wrow0 + wnOff + 0 * 16 + lr];
    const float bv1 = bias[Wrow0 + wnOff + 1 * 16 + lr];
    const float bv2 = bias[Wrow0 + wnOff + 2 * 16 + lr];
    const float bv3 = bias[Wrow0 + wnOff + 3 * 16 + lr];

    const int     blk = tn >> 2;  // 256-col tile fully inside one 1024-col gate block
    const int     lg  = lane >> 4;
    const int64_t BH  = (int64_t)B_DIM * H_DIM;

    auto epi = [&](int m, int n, f32x4 a, float bv) {
        const int64_t rowb = Arow0 + wmOff + m * 16 + lg * 4;
        const int     colo = wnOff + n * 16 + lr;
        if (blk == 2) {  // go -> fp32 output (never re-read: nontemporal)
            float* dst = out + 6 * BH + (Wrow0 - 2 * (int64_t)H_DIM) + colo;
#pragma unroll
            for (int r = 0; r < 4; ++r)
                __builtin_nontemporal_store(sigmoid_f(a[r] + bv), dst + (rowb + r) * H_DIM);
        } else if (blk >= 6) {  // decay -> fp32 output ([B,4H] row-major, never re-read)
            float* dst = out + 2 * BH + (Wrow0 - 6 * (int64_t)H_DIM) + colo;
#pragma unroll
            for (int r = 0; r < 4; ++r)
                __builtin_nontemporal_store(softplus_f(a[r] + bv), dst + (rowb + r) * 4 * H_DIM);
        } else {  // gate -> bf16 workspace (re-read by combine: keep cacheable)
            __bf16* gp = (blk == 0) ? ggi : (blk == 1) ? ggf
                       : (blk == 3) ? ggib : (blk == 4) ? ggfb : gpc;
            __bf16* dst = gp + (int)(Wrow0 & 1023) + colo;
            if (blk == 5) {
#pragma unroll
                for (int r = 0; r < 4; ++r) dst[(rowb + r) * H_DIM] = (__bf16)tanh_f(a[r] + bv);
            } else {
#pragma unroll
                for (int r = 0; r < 4; ++r) dst[(rowb + r) * H_DIM] = (__bf16)sigmoid_f(a[r] + bv);
            }
        }
    };
#define EPI(M, N) epi(M, N, c##M##N, bv##N);
    ACCS(EPI)
#undef EPI
}

// ---------------- combine (cell outputs never re-read: nontemporal stores) ----------------

__global__ void combine_kernel(const __bf16* __restrict__ ggi, const __bf16* __restrict__ ggf,
                               const __bf16* __restrict__ ggib, const __bf16* __restrict__ ggfb,
                               const __bf16* __restrict__ gpc, const float* __restrict__ cp,
                               const float* __restrict__ cbp, float* __restrict__ out) {
    const int64_t BH    = (int64_t)B_DIM * H_DIM;
    const int64_t total = BH / 8;
    for (int64_t i = (int64_t)blockIdx.x * blockDim.x + threadIdx.x; i < total;
         i += (int64_t)gridDim.x * blockDim.x) {
        int64_t e = i << 3;
        bf16x8 vgi  = *reinterpret_cast<const bf16x8*>(ggi + e);
        bf16x8 vgf  = *reinterpret_cast<const bf16x8*>(ggf + e);
        bf16x8 vgib = *reinterpret_cast<const bf16x8*>(ggib + e);
        bf16x8 vgfb = *reinterpret_cast<const bf16x8*>(ggfb + e);
        bf16x8 vpc  = *reinterpret_cast<const bf16x8*>(gpc + e);
        float4 c0  = *reinterpret_cast<const float4*>(cp + e);
        float4 c1  = *reinterpret_cast<const float4*>(cp + e + 4);
        float4 cb0 = *reinterpret_cast<const float4*>(cbp + e);
        float4 cb1 = *reinterpret_cast<const float4*>(cbp + e + 4);
        float cpa[8] = {c0.x, c0.y, c0.z, c0.w, c1.x, c1.y, c1.z, c1.w};
        float cba[8] = {cb0.x, cb0.y, cb0.z, cb0.w, cb1.x, cb1.y, cb1.z, cb1.w};
        float ci[8], cbi[8];
#pragma unroll
        for (int j = 0; j < 8; ++j) {
            float pc = (float)vpc[j];
            ci[j]  = (float)vgf[j]  * cpa[j] + (float)vgi[j]  * pc;
            cbi[j] = (float)vgfb[j] * cba[j] + (float)vgib[j] * pc;
        }
        f32x4 ci0 = {ci[0], ci[1], ci[2], ci[3]};
        f32x4 ci1 = {ci[4], ci[5], ci[6], ci[7]};
        f32x4 cb0v = {cbi[0], cbi[1], cbi[2], cbi[3]};
        f32x4 cb1v = {cbi[4], cbi[5], cbi[6], cbi[7]};
        f32x4* o0 = reinterpret_cast<f32x4*>(out + e);
        __builtin_nontemporal_store(ci0, &o0[0]);
        __builtin_nontemporal_store(ci1, &o0[1]);
        f32x4* o1 = reinterpret_cast<f32x4*>(out + BH + e);
        __builtin_nontemporal_store(cb0v, &o1[0]);
        __builtin_nontemporal_store(cb1v, &o1[1]);
    }
}

// ---------------- launch ----------------

extern "C" void kernel_launch(void* const* d_in, const int* in_sizes, int n_in,
                              void* d_out, int out_size, void* d_ws, size_t ws_size,
                              hipStream_t stream) {
    const float* x   = (const float*)d_in[0];
    const float* h   = (const float*)d_in[1];
    const float* cp  = (const float*)d_in[2];
    const float* cbp = (const float*)d_in[3];
    const float* Wi  = (const float*)d_in[4];
    const float* bi  = (const float*)d_in[5];
    const float* Wf  = (const float*)d_in[6];
    const float* bfo = (const float*)d_in[7];
    const float* Wo  = (const float*)d_in[8];
    const float* bo  = (const float*)d_in[9];
    const float* Wib = (const float*)d_in[10];
    const float* bib = (const float*)d_in[11];
    const float* Wfb = (const float*)d_in[12];
    const float* bfb = (const float*)d_in[13];
    const float* Wpc = (const float*)d_in[14];
    const float* bpc = (const float*)d_in[15];
    const float* Wd  = (const float*)d_in[16];
    const float* bd  = (const float*)d_in[17];
    float* out = (float*)d_out;

    char* ws = (char*)d_ws;
    __bf16* xh   = (__bf16*)ws;
    __bf16* Wb   = (__bf16*)(ws + 33554432);
    float*  bias = (float*)(ws + 75497472);
    __bf16* ggi  = (__bf16*)(ws + 75538432);
    const size_t BH = (size_t)B_DIM * H_DIM;
    __bf16* ggf  = ggi + BH;
    __bf16* ggib = ggf + BH;
    __bf16* ggfb = ggib + BH;
    __bf16* gpc  = ggfb + BH;

    pack_xh_kernel<<<2048, 256, 0, stream>>>(x, h, xh);
    pack_W_kernel<<<2048, 256, 0, stream>>>(Wi, Wf, Wo, Wib, Wfb, Wpc, Wd, Wb);
    pack_bias_kernel<<<40, 256, 0, stream>>>(bi, bfo, bo, bib, bfb, bpc, bd, bias);

    const int grid = (B_DIM / 256) * (N_DIM / 256);  // 1280
    gemm_fused<<<grid, 512, 0, stream>>>(xh, Wb, bias, out, ggi, ggf, ggib, ggfb, gpc);

    combine_kernel<<<4096, 256, 0, stream>>>(ggi, ggf, ggib, ggfb, gpc, cp, cbp, out);
}

// Round 6
// 549.524 us; speedup vs baseline: 1.7067x; 1.3321x over previous
//
#include <hip/hip_runtime.h>
#include <hip/hip_bf16.h>
#include <cstdint>
#include <cmath>

#define B_DIM 8192
#define H_DIM 1024
#define K_DIM 2048   // 2H
#define N_DIM 10240  // 10H

typedef __bf16 bf16x8 __attribute__((ext_vector_type(8)));
typedef float  f32x4  __attribute__((ext_vector_type(4)));

static __device__ __forceinline__ float sigmoid_f(float z) {
    return 1.0f / (1.0f + __expf(-z));
}
static __device__ __forceinline__ float tanh_f(float z) {
    return 1.0f - 2.0f / (1.0f + __expf(2.0f * z));
}
static __device__ __forceinline__ float softplus_f(float z) {
    return fmaxf(z, 0.0f) + log1pf(__expf(-fabsf(z)));
}

static __device__ __forceinline__ void store_bf16x4(__bf16* p, float4 v) {
    alignas(8) __bf16 t[4] = {(__bf16)v.x, (__bf16)v.y, (__bf16)v.z, (__bf16)v.w};
    *reinterpret_cast<uint2*>(p) = *reinterpret_cast<const uint2*>(t);
}

static __device__ __forceinline__ void gload_lds16(const void* g, void* l) {
    auto* gp = reinterpret_cast<__attribute__((address_space(1))) unsigned int*>(
        reinterpret_cast<uintptr_t>(g));
    auto* lp = reinterpret_cast<__attribute__((address_space(3))) unsigned int*>(
        reinterpret_cast<uintptr_t>(l));
    __builtin_amdgcn_global_load_lds(gp, lp, 16, 0, 0);
}

// ---------------- pack kernels (unchanged) ----------------

__global__ void pack_xh_kernel(const float* __restrict__ x, const float* __restrict__ h,
                               __bf16* __restrict__ xh) {
    const int64_t total = (int64_t)B_DIM * K_DIM / 4;
    for (int64_t i = (int64_t)blockIdx.x * blockDim.x + threadIdx.x; i < total;
         i += (int64_t)gridDim.x * blockDim.x) {
        int64_t e = i << 2;
        int64_t b = e >> 11;
        int     c = (int)(e & 2047);
        const float* src = (c < H_DIM) ? (x + b * H_DIM + c) : (h + b * H_DIM + (c - H_DIM));
        float4 v = *reinterpret_cast<const float4*>(src);
        store_bf16x4(xh + e, v);
    }
}

__global__ void pack_W_kernel(const float* __restrict__ w0, const float* __restrict__ w1,
                              const float* __restrict__ w2, const float* __restrict__ w3,
                              const float* __restrict__ w4, const float* __restrict__ w5,
                              const float* __restrict__ wd, __bf16* __restrict__ dst) {
    const int64_t total = (int64_t)N_DIM * K_DIM / 4;
    for (int64_t i = (int64_t)blockIdx.x * blockDim.x + threadIdx.x; i < total;
         i += (int64_t)gridDim.x * blockDim.x) {
        int64_t e   = i << 2;
        int     blk = (int)(e >> 21);
        const float* src;
        int64_t off;
        if (blk < 6) {
            src = (blk == 0) ? w0 : (blk == 1) ? w1 : (blk == 2) ? w2
                : (blk == 3) ? w3 : (blk == 4) ? w4 : w5;
            off = e - ((int64_t)blk << 21);
        } else {
            src = wd;
            off = e - ((int64_t)6 << 21);
        }
        float4 v = *reinterpret_cast<const float4*>(src + off);
        store_bf16x4(dst + e, v);
    }
}

__global__ void pack_bias_kernel(const float* __restrict__ b0, const float* __restrict__ b1,
                                 const float* __restrict__ b2, const float* __restrict__ b3,
                                 const float* __restrict__ b4, const float* __restrict__ b5,
                                 const float* __restrict__ bd, float* __restrict__ dst) {
    int i = blockIdx.x * blockDim.x + threadIdx.x;
    if (i >= N_DIM) return;
    int blk = i >> 10;
    float v;
    if (blk < 6) {
        const float* s = (blk == 0) ? b0 : (blk == 1) ? b1 : (blk == 2) ? b2
                       : (blk == 3) ? b3 : (blk == 4) ? b4 : b5;
        v = s[i - (blk << 10)];
    } else {
        v = bd[i - (6 << 10)];
    }
    dst[i] = v;
}

// ---------------- GEMM: m97 structure ----------------
// 128x128 tile, BK=64, 4 waves (256 thr), SINGLE-buffered 32KB LDS, 2x __syncthreads per
// K-step, global_load_lds width-16, linear LDS (no swizzle: T2 null in 2-phase regime),
// compiler-scheduled waits. 5120 blocks -> ~3 blocks/CU (launch_bounds(256,3)): inter-block
// wave overlap hides the barrier-drain + staging latency (m114/m97: 912 TF proven on HW).
// XCD map: r2-winning family (tm band per XCD, lockstep tn sweep).

#define MFMA_(Af, Bf, C) __builtin_amdgcn_mfma_f32_16x16x32_bf16(Af, Bf, C, 0, 0, 0)

#define ACCS(F) \
    F(0,0) F(0,1) F(0,2) F(0,3) F(1,0) F(1,1) F(1,2) F(1,3) \
    F(2,0) F(2,1) F(2,2) F(2,3) F(3,0) F(3,1) F(3,2) F(3,3)

#define LDFRAG(P, I, KH) (*reinterpret_cast<const bf16x8*>((P) + (I) * 1024 + (KH) * 32))

#define READF(KH) \
    a0 = LDFRAG(aRd, 0, KH); a1 = LDFRAG(aRd, 1, KH); \
    a2 = LDFRAG(aRd, 2, KH); a3 = LDFRAG(aRd, 3, KH); \
    b0 = LDFRAG(bRd, 0, KH); b1 = LDFRAG(bRd, 1, KH); \
    b2 = LDFRAG(bRd, 2, KH); b3 = LDFRAG(bRd, 3, KH);

#define MFMA_ALL \
    c00 = MFMA_(a0, b0, c00); c01 = MFMA_(a0, b1, c01); \
    c02 = MFMA_(a0, b2, c02); c03 = MFMA_(a0, b3, c03); \
    c10 = MFMA_(a1, b0, c10); c11 = MFMA_(a1, b1, c11); \
    c12 = MFMA_(a1, b2, c12); c13 = MFMA_(a1, b3, c13); \
    c20 = MFMA_(a2, b0, c20); c21 = MFMA_(a2, b1, c21); \
    c22 = MFMA_(a2, b2, c22); c23 = MFMA_(a2, b3, c23); \
    c30 = MFMA_(a3, b0, c30); c31 = MFMA_(a3, b1, c31); \
    c32 = MFMA_(a3, b2, c32); c33 = MFMA_(a3, b3, c33);

__global__ __launch_bounds__(256, 3) void gemm_fused(
    const __bf16* __restrict__ A,     // [8192][2048]
    const __bf16* __restrict__ W,     // [10240][2048]
    const float* __restrict__ bias,   // [10240]
    float* __restrict__ out,
    __bf16* __restrict__ ggi, __bf16* __restrict__ ggf,
    __bf16* __restrict__ ggib, __bf16* __restrict__ ggfb,
    __bf16* __restrict__ gpc) {
    __shared__ __bf16 As[8192];   // [128][64]
    __shared__ __bf16 Bs[8192];   // [128][64]

    const int NT_N = N_DIM / 128;            // 80
    const int nwg  = (B_DIM / 128) * NT_N;   // 5120
    const int bid  = blockIdx.x;
    const int swz  = (bid & 7) * (nwg >> 3) + (bid >> 3);
    const int tm   = swz / NT_N;             // 0..63 (8-row band per XCD)
    const int tn   = swz % NT_N;             // 0..79 (lockstep sweep across XCDs)

    const int t     = threadIdx.x;
    const int lane  = t & 63;
    const int w     = t >> 6;          // 0..3
    const int wmOff = (w >> 1) << 6;   // 0 or 64
    const int wnOff = (w & 1) << 6;    // 0 or 64
    const int lr    = lane & 15;
    const int kg    = lane >> 4;       // 0..3

    const int64_t Arow0 = (int64_t)tm * 128;
    const int64_t Wrow0 = (int64_t)tn * 128;

#define DA(M, N) f32x4 c##M##N = {0.f, 0.f, 0.f, 0.f};
    ACCS(DA)
#undef DA
    bf16x8 a0, a1, a2, a3, b0, b1, b2, b3;

    // staging: call rj covers rows [rj*32, rj*32+32), cols [k0, k0+64). lane row = t>>3,
    // col chunk = (t&7)*8. LDS dest = base + t*16B (per-wave uniform base + lane*16). linear.
    const __bf16* aSrc = A + (Arow0 + (t >> 3)) * (int64_t)K_DIM + ((t & 7) << 3);
    const __bf16* bSrc = W + (Wrow0 + (t >> 3)) * (int64_t)K_DIM + ((t & 7) << 3);
    __bf16* ldsA = As + t * 8;
    __bf16* ldsB = Bs + t * 8;

    // fragment read bases (linear layout: row*64 + kh*32 + kg*8)
    const __bf16* aRd = As + (wmOff + lr) * 64 + kg * 8;
    const __bf16* bRd = Bs + (wnOff + lr) * 64 + kg * 8;

#pragma unroll 1
    for (int kt = 0; kt < 32; ++kt) {
        const int k0 = kt << 6;
        __syncthreads();   // everyone done reading previous tile
        gload_lds16(aSrc + 0 * (32 * K_DIM) + k0, ldsA + 0 * 2048);
        gload_lds16(aSrc + 1 * (32 * K_DIM) + k0, ldsA + 1 * 2048);
        gload_lds16(aSrc + 2 * (32 * K_DIM) + k0, ldsA + 2 * 2048);
        gload_lds16(aSrc + 3 * (32 * K_DIM) + k0, ldsA + 3 * 2048);
        gload_lds16(bSrc + 0 * (32 * K_DIM) + k0, ldsB + 0 * 2048);
        gload_lds16(bSrc + 1 * (32 * K_DIM) + k0, ldsB + 1 * 2048);
        gload_lds16(bSrc + 2 * (32 * K_DIM) + k0, ldsB + 2 * 2048);
        gload_lds16(bSrc + 3 * (32 * K_DIM) + k0, ldsB + 3 * 2048);
        __syncthreads();   // compiler drains vmcnt before barrier: tile landed
        READF(0)
        MFMA_ALL
        READF(1)
        MFMA_ALL
    }
    __syncthreads();

    // ---- fused epilogue (bias folded here) ----
    const float bv0 = bias[Wrow0 + wnOff + 0 * 16 + lr];
    const float bv1 = bias[Wrow0 + wnOff + 1 * 16 + lr];
    const float bv2 = bias[Wrow0 + wnOff + 2 * 16 + lr];
    const float bv3 = bias[Wrow0 + wnOff + 3 * 16 + lr];

    const int     blk = tn >> 3;  // 128-col tile fully inside one 1024-col gate block
    const int     lg  = lane >> 4;
    const int64_t BH  = (int64_t)B_DIM * H_DIM;

    auto epi = [&](int m, int n, f32x4 a, float bv) {
        const int64_t rowb = Arow0 + wmOff + m * 16 + lg * 4;
        const int     colo = wnOff + n * 16 + lr;
        if (blk == 2) {  // go -> fp32 output (never re-read: nontemporal)
            float* dst = out + 6 * BH + (Wrow0 - 2 * (int64_t)H_DIM) + colo;
#pragma unroll
            for (int r = 0; r < 4; ++r)
                __builtin_nontemporal_store(sigmoid_f(a[r] + bv), dst + (rowb + r) * H_DIM);
        } else if (blk >= 6) {  // decay -> fp32 output ([B,4H] row-major, never re-read)
            float* dst = out + 2 * BH + (Wrow0 - 6 * (int64_t)H_DIM) + colo;
#pragma unroll
            for (int r = 0; r < 4; ++r)
                __builtin_nontemporal_store(softplus_f(a[r] + bv), dst + (rowb + r) * 4 * H_DIM);
        } else {  // gate -> bf16 workspace (re-read by combine: keep cacheable)
            __bf16* gp = (blk == 0) ? ggi : (blk == 1) ? ggf
                       : (blk == 3) ? ggib : (blk == 4) ? ggfb : gpc;
            __bf16* dst = gp + (int)(Wrow0 & 1023) + colo;
            if (blk == 5) {
#pragma unroll
                for (int r = 0; r < 4; ++r) dst[(rowb + r) * H_DIM] = (__bf16)tanh_f(a[r] + bv);
            } else {
#pragma unroll
                for (int r = 0; r < 4; ++r) dst[(rowb + r) * H_DIM] = (__bf16)sigmoid_f(a[r] + bv);
            }
        }
    };
#define EPI(M, N) epi(M, N, c##M##N, bv##N);
    ACCS(EPI)
#undef EPI
}

// ---------------- combine (cell outputs never re-read: nontemporal stores) ----------------

__global__ void combine_kernel(const __bf16* __restrict__ ggi, const __bf16* __restrict__ ggf,
                               const __bf16* __restrict__ ggib, const __bf16* __restrict__ ggfb,
                               const __bf16* __restrict__ gpc, const float* __restrict__ cp,
                               const float* __restrict__ cbp, float* __restrict__ out) {
    const int64_t BH    = (int64_t)B_DIM * H_DIM;
    const int64_t total = BH / 8;
    for (int64_t i = (int64_t)blockIdx.x * blockDim.x + threadIdx.x; i < total;
         i += (int64_t)gridDim.x * blockDim.x) {
        int64_t e = i << 3;
        bf16x8 vgi  = *reinterpret_cast<const bf16x8*>(ggi + e);
        bf16x8 vgf  = *reinterpret_cast<const bf16x8*>(ggf + e);
        bf16x8 vgib = *reinterpret_cast<const bf16x8*>(ggib + e);
        bf16x8 vgfb = *reinterpret_cast<const bf16x8*>(ggfb + e);
        bf16x8 vpc  = *reinterpret_cast<const bf16x8*>(gpc + e);
        float4 c0  = *reinterpret_cast<const float4*>(cp + e);
        float4 c1  = *reinterpret_cast<const float4*>(cp + e + 4);
        float4 cb0 = *reinterpret_cast<const float4*>(cbp + e);
        float4 cb1 = *reinterpret_cast<const float4*>(cbp + e + 4);
        float cpa[8] = {c0.x, c0.y, c0.z, c0.w, c1.x, c1.y, c1.z, c1.w};
        float cba[8] = {cb0.x, cb0.y, cb0.z, cb0.w, cb1.x, cb1.y, cb1.z, cb1.w};
        float ci[8], cbi[8];
#pragma unroll
        for (int j = 0; j < 8; ++j) {
            float pc = (float)vpc[j];
            ci[j]  = (float)vgf[j]  * cpa[j] + (float)vgi[j]  * pc;
            cbi[j] = (float)vgfb[j] * cba[j] + (float)vgib[j] * pc;
        }
        f32x4 ci0 = {ci[0], ci[1], ci[2], ci[3]};
        f32x4 ci1 = {ci[4], ci[5], ci[6], ci[7]};
        f32x4 cb0v = {cbi[0], cbi[1], cbi[2], cbi[3]};
        f32x4 cb1v = {cbi[4], cbi[5], cbi[6], cbi[7]};
        f32x4* o0 = reinterpret_cast<f32x4*>(out + e);
        __builtin_nontemporal_store(ci0, &o0[0]);
        __builtin_nontemporal_store(ci1, &o0[1]);
        f32x4* o1 = reinterpret_cast<f32x4*>(out + BH + e);
        __builtin_nontemporal_store(cb0v, &o1[0]);
        __builtin_nontemporal_store(cb1v, &o1[1]);
    }
}

// ---------------- launch ----------------

extern "C" void kernel_launch(void* const* d_in, const int* in_sizes, int n_in,
                              void* d_out, int out_size, void* d_ws, size_t ws_size,
                              hipStream_t stream) {
    const float* x   = (const float*)d_in[0];
    const float* h   = (const float*)d_in[1];
    const float* cp  = (const float*)d_in[2];
    const float* cbp = (const float*)d_in[3];
    const float* Wi  = (const float*)d_in[4];
    const float* bi  = (const float*)d_in[5];
    const float* Wf  = (const float*)d_in[6];
    const float* bfo = (const float*)d_in[7];
    const float* Wo  = (const float*)d_in[8];
    const float* bo  = (const float*)d_in[9];
    const float* Wib = (const float*)d_in[10];
    const float* bib = (const float*)d_in[11];
    const float* Wfb = (const float*)d_in[12];
    const float* bfb = (const float*)d_in[13];
    const float* Wpc = (const float*)d_in[14];
    const float* bpc = (const float*)d_in[15];
    const float* Wd  = (const float*)d_in[16];
    const float* bd  = (const float*)d_in[17];
    float* out = (float*)d_out;

    char* ws = (char*)d_ws;
    __bf16* xh   = (__bf16*)ws;
    __bf16* Wb   = (__bf16*)(ws + 33554432);
    float*  bias = (float*)(ws + 75497472);
    __bf16* ggi  = (__bf16*)(ws + 75538432);
    const size_t BH = (size_t)B_DIM * H_DIM;
    __bf16* ggf  = ggi + BH;
    __bf16* ggib = ggf + BH;
    __bf16* ggfb = ggib + BH;
    __bf16* gpc  = ggfb + BH;

    pack_xh_kernel<<<2048, 256, 0, stream>>>(x, h, xh);
    pack_W_kernel<<<2048, 256, 0, stream>>>(Wi, Wf, Wo, Wib, Wfb, Wpc, Wd, Wb);
    pack_bias_kernel<<<40, 256, 0, stream>>>(bi, bfo, bo, bib, bfb, bpc, bd, bias);

    const int grid = (B_DIM / 128) * (N_DIM / 128);  // 5120
    gemm_fused<<<grid, 256, 0, stream>>>(xh, Wb, bias, out, ggi, ggf, ggib, ggfb, gpc);

    combine_kernel<<<4096, 256, 0, stream>>>(ggi, ggf, ggib, ggfb, gpc, cp, cbp, out);
}

// Round 7
// 522.436 us; speedup vs baseline: 1.7952x; 1.0518x over previous
//
#include <hip/hip_runtime.h>
#include <hip/hip_bf16.h>
#include <cstdint>
#include <cmath>

#define B_DIM 8192
#define H_DIM 1024
#define K_DIM 2048   // 2H
#define N_DIM 10240  // 10H

typedef __bf16 bf16x8 __attribute__((ext_vector_type(8)));
typedef float  f32x4  __attribute__((ext_vector_type(4)));

static __device__ __forceinline__ float sigmoid_f(float z) {
    return 1.0f / (1.0f + __expf(-z));
}
static __device__ __forceinline__ float tanh_f(float z) {
    return 1.0f - 2.0f / (1.0f + __expf(2.0f * z));
}
static __device__ __forceinline__ float softplus_f(float z) {
    return fmaxf(z, 0.0f) + log1pf(__expf(-fabsf(z)));
}

static __device__ __forceinline__ void store_bf16x4(__bf16* p, float4 v) {
    alignas(8) __bf16 t[4] = {(__bf16)v.x, (__bf16)v.y, (__bf16)v.z, (__bf16)v.w};
    *reinterpret_cast<uint2*>(p) = *reinterpret_cast<const uint2*>(t);
}

static __device__ __forceinline__ void gload_lds16(const void* g, void* l) {
    auto* gp = reinterpret_cast<__attribute__((address_space(1))) unsigned int*>(
        reinterpret_cast<uintptr_t>(g));
    auto* lp = reinterpret_cast<__attribute__((address_space(3))) unsigned int*>(
        reinterpret_cast<uintptr_t>(l));
    __builtin_amdgcn_global_load_lds(gp, lp, 16, 0, 0);
}

// ---------------- pack kernels (unchanged) ----------------

__global__ void pack_xh_kernel(const float* __restrict__ x, const float* __restrict__ h,
                               __bf16* __restrict__ xh) {
    const int64_t total = (int64_t)B_DIM * K_DIM / 4;
    for (int64_t i = (int64_t)blockIdx.x * blockDim.x + threadIdx.x; i < total;
         i += (int64_t)gridDim.x * blockDim.x) {
        int64_t e = i << 2;
        int64_t b = e >> 11;
        int     c = (int)(e & 2047);
        const float* src = (c < H_DIM) ? (x + b * H_DIM + c) : (h + b * H_DIM + (c - H_DIM));
        float4 v = *reinterpret_cast<const float4*>(src);
        store_bf16x4(xh + e, v);
    }
}

__global__ void pack_W_kernel(const float* __restrict__ w0, const float* __restrict__ w1,
                              const float* __restrict__ w2, const float* __restrict__ w3,
                              const float* __restrict__ w4, const float* __restrict__ w5,
                              const float* __restrict__ wd, __bf16* __restrict__ dst) {
    const int64_t total = (int64_t)N_DIM * K_DIM / 4;
    for (int64_t i = (int64_t)blockIdx.x * blockDim.x + threadIdx.x; i < total;
         i += (int64_t)gridDim.x * blockDim.x) {
        int64_t e   = i << 2;
        int     blk = (int)(e >> 21);
        const float* src;
        int64_t off;
        if (blk < 6) {
            src = (blk == 0) ? w0 : (blk == 1) ? w1 : (blk == 2) ? w2
                : (blk == 3) ? w3 : (blk == 4) ? w4 : w5;
            off = e - ((int64_t)blk << 21);
        } else {
            src = wd;
            off = e - ((int64_t)6 << 21);
        }
        float4 v = *reinterpret_cast<const float4*>(src + off);
        store_bf16x4(dst + e, v);
    }
}

__global__ void pack_bias_kernel(const float* __restrict__ b0, const float* __restrict__ b1,
                                 const float* __restrict__ b2, const float* __restrict__ b3,
                                 const float* __restrict__ b4, const float* __restrict__ b5,
                                 const float* __restrict__ bd, float* __restrict__ dst) {
    int i = blockIdx.x * blockDim.x + threadIdx.x;
    if (i >= N_DIM) return;
    int blk = i >> 10;
    float v;
    if (blk < 6) {
        const float* s = (blk == 0) ? b0 : (blk == 1) ? b1 : (blk == 2) ? b2
                       : (blk == 3) ? b3 : (blk == 4) ? b4 : b5;
        v = s[i - (blk << 10)];
    } else {
        v = bd[i - (6 << 10)];
    }
    dst[i] = v;
}

// ---------------- GEMM: m97 structure + XOR bank-conflict swizzle ----------------
// Round-6 kernel (128x128, BK=64, 4 waves, single-buffer 32KB LDS, 2x __syncthreads/K-step,
// ~3 blocks/CU inter-block overlap -> 494us) measured SQ_LDS_BANK_CONFLICT=1.26e8/dispatch
// (~41% of all CU cycles): linear [128][64] reads are a 16-way conflict (lanes stride 128B).
// Single change this round: store logical 16B-chunk c of row r at physical chunk c^(r&7).
// global_load_lds dest stays LINEAR (HW requirement); the permutation is applied on the
// GLOBAL source (chunk = (t&7)^((t>>3)&7), exact r2-kernel machinery, harness-verified) and
// on the read side it folds into per-lane constant bases (kh=1 base = kh=0 base ^ 64).

#define MFMA_(Af, Bf, C) __builtin_amdgcn_mfma_f32_16x16x32_bf16(Af, Bf, C, 0, 0, 0)

#define ACCS(F) \
    F(0,0) F(0,1) F(0,2) F(0,3) F(1,0) F(1,1) F(1,2) F(1,3) \
    F(2,0) F(2,1) F(2,2) F(2,3) F(3,0) F(3,1) F(3,2) F(3,3)

#define READF(KH) \
    a0 = ldA(0, KH); a1 = ldA(1, KH); a2 = ldA(2, KH); a3 = ldA(3, KH); \
    b0 = ldB(0, KH); b1 = ldB(1, KH); b2 = ldB(2, KH); b3 = ldB(3, KH);

#define MFMA_ALL \
    c00 = MFMA_(a0, b0, c00); c01 = MFMA_(a0, b1, c01); \
    c02 = MFMA_(a0, b2, c02); c03 = MFMA_(a0, b3, c03); \
    c10 = MFMA_(a1, b0, c10); c11 = MFMA_(a1, b1, c11); \
    c12 = MFMA_(a1, b2, c12); c13 = MFMA_(a1, b3, c13); \
    c20 = MFMA_(a2, b0, c20); c21 = MFMA_(a2, b1, c21); \
    c22 = MFMA_(a2, b2, c22); c23 = MFMA_(a2, b3, c23); \
    c30 = MFMA_(a3, b0, c30); c31 = MFMA_(a3, b1, c31); \
    c32 = MFMA_(a3, b2, c32); c33 = MFMA_(a3, b3, c33);

__global__ __launch_bounds__(256, 3) void gemm_fused(
    const __bf16* __restrict__ A,     // [8192][2048]
    const __bf16* __restrict__ W,     // [10240][2048]
    const float* __restrict__ bias,   // [10240]
    float* __restrict__ out,
    __bf16* __restrict__ ggi, __bf16* __restrict__ ggf,
    __bf16* __restrict__ ggib, __bf16* __restrict__ ggfb,
    __bf16* __restrict__ gpc) {
    __shared__ __bf16 As[8192];   // [128][64], chunk-swizzled
    __shared__ __bf16 Bs[8192];   // [128][64], chunk-swizzled

    const int NT_N = N_DIM / 128;            // 80
    const int nwg  = (B_DIM / 128) * NT_N;   // 5120
    const int bid  = blockIdx.x;
    const int swz  = (bid & 7) * (nwg >> 3) + (bid >> 3);
    const int tm   = swz / NT_N;             // 0..63 (8-row band per XCD)
    const int tn   = swz % NT_N;             // 0..79 (lockstep sweep across XCDs)

    const int t     = threadIdx.x;
    const int lane  = t & 63;
    const int w     = t >> 6;          // 0..3
    const int wmOff = (w >> 1) << 6;   // 0 or 64
    const int wnOff = (w & 1) << 6;    // 0 or 64
    const int lr    = lane & 15;
    const int kg    = lane >> 4;       // 0..3

    const int64_t Arow0 = (int64_t)tm * 128;
    const int64_t Wrow0 = (int64_t)tn * 128;

#define DA(M, N) f32x4 c##M##N = {0.f, 0.f, 0.f, 0.f};
    ACCS(DA)
#undef DA
    bf16x8 a0, a1, a2, a3, b0, b1, b2, b3;

    // staging: thread t covers LDS row (t>>3), physical chunk (t&7); it must LOAD the
    // inverse-swizzled global chunk (t&7)^((t>>3)&7). LDS dest linear: base + t*16B.
    const int srcChunk = ((t & 7) ^ ((t >> 3) & 7)) << 3;  // elements
    const __bf16* aSrc = A + (Arow0 + (t >> 3)) * (int64_t)K_DIM + srcChunk;
    const __bf16* bSrc = W + (Wrow0 + (t >> 3)) * (int64_t)K_DIM + srcChunk;
    __bf16* ldsA = As + t * 8;
    __bf16* ldsB = Bs + t * 8;

    // swizzled fragment-read bases: logical chunk c=kg+4*kh of row r lives at byte
    // r*128 + ((c^(r&7))<<4). Per-lane r=wmOff+lr (r&7 = lr&7) and kg are constants;
    // kh=1 flips chunk bit2 -> base^64. m advances 16 rows = +2048B (r&7 unchanged).
    const int xr  = lr & 7;
    const int ca  = kg ^ xr;                 // logical chunk for kh=0
    const char* aRd0 = reinterpret_cast<const char*>(As) + (wmOff + lr) * 128 + (ca << 4);
    const char* aRd1 = reinterpret_cast<const char*>(As) + (wmOff + lr) * 128 + ((ca ^ 4) << 4);
    const char* bRd0 = reinterpret_cast<const char*>(Bs) + (wnOff + lr) * 128 + (ca << 4);
    const char* bRd1 = reinterpret_cast<const char*>(Bs) + (wnOff + lr) * 128 + ((ca ^ 4) << 4);

    auto ldA = [&](int m, int kh) {
        return *reinterpret_cast<const bf16x8*>((kh ? aRd1 : aRd0) + m * 2048);
    };
    auto ldB = [&](int n, int kh) {
        return *reinterpret_cast<const bf16x8*>((kh ? bRd1 : bRd0) + n * 2048);
    };

#pragma unroll 1
    for (int kt = 0; kt < 32; ++kt) {
        const int k0 = kt << 6;
        __syncthreads();   // everyone done reading previous tile
        gload_lds16(aSrc + 0 * (32 * K_DIM) + k0, ldsA + 0 * 2048);
        gload_lds16(aSrc + 1 * (32 * K_DIM) + k0, ldsA + 1 * 2048);
        gload_lds16(aSrc + 2 * (32 * K_DIM) + k0, ldsA + 2 * 2048);
        gload_lds16(aSrc + 3 * (32 * K_DIM) + k0, ldsA + 3 * 2048);
        gload_lds16(bSrc + 0 * (32 * K_DIM) + k0, ldsB + 0 * 2048);
        gload_lds16(bSrc + 1 * (32 * K_DIM) + k0, ldsB + 1 * 2048);
        gload_lds16(bSrc + 2 * (32 * K_DIM) + k0, ldsB + 2 * 2048);
        gload_lds16(bSrc + 3 * (32 * K_DIM) + k0, ldsB + 3 * 2048);
        __syncthreads();   // compiler drains vmcnt before barrier: tile landed
        READF(0)
        MFMA_ALL
        READF(1)
        MFMA_ALL
    }
    __syncthreads();

    // ---- fused epilogue (bias folded here) ----
    const float bv0 = bias[Wrow0 + wnOff + 0 * 16 + lr];
    const float bv1 = bias[Wrow0 + wnOff + 1 * 16 + lr];
    const float bv2 = bias[Wrow0 + wnOff + 2 * 16 + lr];
    const float bv3 = bias[Wrow0 + wnOff + 3 * 16 + lr];

    const int     blk = tn >> 3;  // 128-col tile fully inside one 1024-col gate block
    const int     lg  = lane >> 4;
    const int64_t BH  = (int64_t)B_DIM * H_DIM;

    auto epi = [&](int m, int n, f32x4 a, float bv) {
        const int64_t rowb = Arow0 + wmOff + m * 16 + lg * 4;
        const int     colo = wnOff + n * 16 + lr;
        if (blk == 2) {  // go -> fp32 output (never re-read: nontemporal)
            float* dst = out + 6 * BH + (Wrow0 - 2 * (int64_t)H_DIM) + colo;
#pragma unroll
            for (int r = 0; r < 4; ++r)
                __builtin_nontemporal_store(sigmoid_f(a[r] + bv), dst + (rowb + r) * H_DIM);
        } else if (blk >= 6) {  // decay -> fp32 output ([B,4H] row-major, never re-read)
            float* dst = out + 2 * BH + (Wrow0 - 6 * (int64_t)H_DIM) + colo;
#pragma unroll
            for (int r = 0; r < 4; ++r)
                __builtin_nontemporal_store(softplus_f(a[r] + bv), dst + (rowb + r) * 4 * H_DIM);
        } else {  // gate -> bf16 workspace (re-read by combine: keep cacheable)
            __bf16* gp = (blk == 0) ? ggi : (blk == 1) ? ggf
                       : (blk == 3) ? ggib : (blk == 4) ? ggfb : gpc;
            __bf16* dst = gp + (int)(Wrow0 & 1023) + colo;
            if (blk == 5) {
#pragma unroll
                for (int r = 0; r < 4; ++r) dst[(rowb + r) * H_DIM] = (__bf16)tanh_f(a[r] + bv);
            } else {
#pragma unroll
                for (int r = 0; r < 4; ++r) dst[(rowb + r) * H_DIM] = (__bf16)sigmoid_f(a[r] + bv);
            }
        }
    };
#define EPI(M, N) epi(M, N, c##M##N, bv##N);
    ACCS(EPI)
#undef EPI
}

// ---------------- combine (cell outputs never re-read: nontemporal stores) ----------------

__global__ void combine_kernel(const __bf16* __restrict__ ggi, const __bf16* __restrict__ ggf,
                               const __bf16* __restrict__ ggib, const __bf16* __restrict__ ggfb,
                               const __bf16* __restrict__ gpc, const float* __restrict__ cp,
                               const float* __restrict__ cbp, float* __restrict__ out) {
    const int64_t BH    = (int64_t)B_DIM * H_DIM;
    const int64_t total = BH / 8;
    for (int64_t i = (int64_t)blockIdx.x * blockDim.x + threadIdx.x; i < total;
         i += (int64_t)gridDim.x * blockDim.x) {
        int64_t e = i << 3;
        bf16x8 vgi  = *reinterpret_cast<const bf16x8*>(ggi + e);
        bf16x8 vgf  = *reinterpret_cast<const bf16x8*>(ggf + e);
        bf16x8 vgib = *reinterpret_cast<const bf16x8*>(ggib + e);
        bf16x8 vgfb = *reinterpret_cast<const bf16x8*>(ggfb + e);
        bf16x8 vpc  = *reinterpret_cast<const bf16x8*>(gpc + e);
        float4 c0  = *reinterpret_cast<const float4*>(cp + e);
        float4 c1  = *reinterpret_cast<const float4*>(cp + e + 4);
        float4 cb0 = *reinterpret_cast<const float4*>(cbp + e);
        float4 cb1 = *reinterpret_cast<const float4*>(cbp + e + 4);
        float cpa[8] = {c0.x, c0.y, c0.z, c0.w, c1.x, c1.y, c1.z, c1.w};
        float cba[8] = {cb0.x, cb0.y, cb0.z, cb0.w, cb1.x, cb1.y, cb1.z, cb1.w};
        float ci[8], cbi[8];
#pragma unroll
        for (int j = 0; j < 8; ++j) {
            float pc = (float)vpc[j];
            ci[j]  = (float)vgf[j]  * cpa[j] + (float)vgi[j]  * pc;
            cbi[j] = (float)vgfb[j] * cba[j] + (float)vgib[j] * pc;
        }
        f32x4 ci0 = {ci[0], ci[1], ci[2], ci[3]};
        f32x4 ci1 = {ci[4], ci[5], ci[6], ci[7]};
        f32x4 cb0v = {cbi[0], cbi[1], cbi[2], cbi[3]};
        f32x4 cb1v = {cbi[4], cbi[5], cbi[6], cbi[7]};
        f32x4* o0 = reinterpret_cast<f32x4*>(out + e);
        __builtin_nontemporal_store(ci0, &o0[0]);
        __builtin_nontemporal_store(ci1, &o0[1]);
        f32x4* o1 = reinterpret_cast<f32x4*>(out + BH + e);
        __builtin_nontemporal_store(cb0v, &o1[0]);
        __builtin_nontemporal_store(cb1v, &o1[1]);
    }
}

// ---------------- launch ----------------

extern "C" void kernel_launch(void* const* d_in, const int* in_sizes, int n_in,
                              void* d_out, int out_size, void* d_ws, size_t ws_size,
                              hipStream_t stream) {
    const float* x   = (const float*)d_in[0];
    const float* h   = (const float*)d_in[1];
    const float* cp  = (const float*)d_in[2];
    const float* cbp = (const float*)d_in[3];
    const float* Wi  = (const float*)d_in[4];
    const float* bi  = (const float*)d_in[5];
    const float* Wf  = (const float*)d_in[6];
    const float* bfo = (const float*)d_in[7];
    const float* Wo  = (const float*)d_in[8];
    const float* bo  = (const float*)d_in[9];
    const float* Wib = (const float*)d_in[10];
    const float* bib = (const float*)d_in[11];
    const float* Wfb = (const float*)d_in[12];
    const float* bfb = (const float*)d_in[13];
    const float* Wpc = (const float*)d_in[14];
    const float* bpc = (const float*)d_in[15];
    const float* Wd  = (const float*)d_in[16];
    const float* bd  = (const float*)d_in[17];
    float* out = (float*)d_out;

    char* ws = (char*)d_ws;
    __bf16* xh   = (__bf16*)ws;
    __bf16* Wb   = (__bf16*)(ws + 33554432);
    float*  bias = (float*)(ws + 75497472);
    __bf16* ggi  = (__bf16*)(ws + 75538432);
    const size_t BH = (size_t)B_DIM * H_DIM;
    __bf16* ggf  = ggi + BH;
    __bf16* ggib = ggf + BH;
    __bf16* ggfb = ggib + BH;
    __bf16* gpc  = ggfb + BH;

    pack_xh_kernel<<<2048, 256, 0, stream>>>(x, h, xh);
    pack_W_kernel<<<2048, 256, 0, stream>>>(Wi, Wf, Wo, Wib, Wfb, Wpc, Wd, Wb);
    pack_bias_kernel<<<40, 256, 0, stream>>>(bi, bfo, bo, bib, bfb, bpc, bd, bias);

    const int grid = (B_DIM / 128) * (N_DIM / 128);  // 5120
    gemm_fused<<<grid, 256, 0, stream>>>(xh, Wb, bias, out, ggi, ggf, ggib, ggfb, gpc);

    combine_kernel<<<4096, 256, 0, stream>>>(ggi, ggf, ggib, ggfb, gpc, cp, cbp, out);
}

// Round 8
// 457.050 us; speedup vs baseline: 2.0520x; 1.1431x over previous
//
#include <hip/hip_runtime.h>
#include <hip/hip_bf16.h>
#include <cstdint>
#include <cmath>

#define B_DIM 8192
#define H_DIM 1024
#define K_DIM 2048   // 2H
#define N_DIM 10240  // 10H

typedef __bf16 bf16x8 __attribute__((ext_vector_type(8)));
typedef float  f32x4  __attribute__((ext_vector_type(4)));

static __device__ __forceinline__ float sigmoid_f(float z) {
    return 1.0f / (1.0f + __expf(-z));
}
static __device__ __forceinline__ float tanh_f(float z) {
    return 1.0f - 2.0f / (1.0f + __expf(2.0f * z));
}
static __device__ __forceinline__ float softplus_f(float z) {
    return fmaxf(z, 0.0f) + log1pf(__expf(-fabsf(z)));
}

static __device__ __forceinline__ void store_bf16x4(__bf16* p, float4 v) {
    alignas(8) __bf16 t[4] = {(__bf16)v.x, (__bf16)v.y, (__bf16)v.z, (__bf16)v.w};
    *reinterpret_cast<uint2*>(p) = *reinterpret_cast<const uint2*>(t);
}

static __device__ __forceinline__ void gload_lds16(const void* g, void* l) {
    auto* gp = reinterpret_cast<__attribute__((address_space(1))) unsigned int*>(
        reinterpret_cast<uintptr_t>(g));
    auto* lp = reinterpret_cast<__attribute__((address_space(3))) unsigned int*>(
        reinterpret_cast<uintptr_t>(l));
    __builtin_amdgcn_global_load_lds(gp, lp, 16, 0, 0);
}

// ---------------- pack kernels (unchanged) ----------------

__global__ void pack_xh_kernel(const float* __restrict__ x, const float* __restrict__ h,
                               __bf16* __restrict__ xh) {
    const int64_t total = (int64_t)B_DIM * K_DIM / 4;
    for (int64_t i = (int64_t)blockIdx.x * blockDim.x + threadIdx.x; i < total;
         i += (int64_t)gridDim.x * blockDim.x) {
        int64_t e = i << 2;
        int64_t b = e >> 11;
        int     c = (int)(e & 2047);
        const float* src = (c < H_DIM) ? (x + b * H_DIM + c) : (h + b * H_DIM + (c - H_DIM));
        float4 v = *reinterpret_cast<const float4*>(src);
        store_bf16x4(xh + e, v);
    }
}

__global__ void pack_W_kernel(const float* __restrict__ w0, const float* __restrict__ w1,
                              const float* __restrict__ w2, const float* __restrict__ w3,
                              const float* __restrict__ w4, const float* __restrict__ w5,
                              const float* __restrict__ wd, __bf16* __restrict__ dst) {
    const int64_t total = (int64_t)N_DIM * K_DIM / 4;
    for (int64_t i = (int64_t)blockIdx.x * blockDim.x + threadIdx.x; i < total;
         i += (int64_t)gridDim.x * blockDim.x) {
        int64_t e   = i << 2;
        int     blk = (int)(e >> 21);
        const float* src;
        int64_t off;
        if (blk < 6) {
            src = (blk == 0) ? w0 : (blk == 1) ? w1 : (blk == 2) ? w2
                : (blk == 3) ? w3 : (blk == 4) ? w4 : w5;
            off = e - ((int64_t)blk << 21);
        } else {
            src = wd;
            off = e - ((int64_t)6 << 21);
        }
        float4 v = *reinterpret_cast<const float4*>(src + off);
        store_bf16x4(dst + e, v);
    }
}

__global__ void pack_bias_kernel(const float* __restrict__ b0, const float* __restrict__ b1,
                                 const float* __restrict__ b2, const float* __restrict__ b3,
                                 const float* __restrict__ b4, const float* __restrict__ b5,
                                 const float* __restrict__ bd, float* __restrict__ dst) {
    int i = blockIdx.x * blockDim.x + threadIdx.x;
    if (i >= N_DIM) return;
    int blk = i >> 10;
    float v;
    if (blk < 6) {
        const float* s = (blk == 0) ? b0 : (blk == 1) ? b1 : (blk == 2) ? b2
                       : (blk == 3) ? b3 : (blk == 4) ? b4 : b5;
        v = s[i - (blk << 10)];
    } else {
        v = bd[i - (6 << 10)];
    }
    dst[i] = v;
}

// ---------------- GEMM: m97 structure + XOR swizzle + 2D-chunked XCD map ----------------
// r7 (128x128, 4 waves, single-buffer 32KB LDS, swizzled reads, ~3 blocks/CU) = 457us,
// conflicts 0, MfmaUtil 34.5, HBM 3.59 TB/s (57% achievable), FETCH 1.33GB vs 75MB
// compulsory. Theory: linear tn sweep streams all of W (42MB) through each XCD L2 per
// tm row. Single change: per-XCD 2D chunking. Keep tm band of 8; sweep tn in chunks of
// 10 (8 tm x 10 tn = 80 blocks ~ XCD concurrent capacity). A band (4MB) persists in L2
// across chunks; W chunk (5MB) reused 8x before moving on; XCDs lockstep on tn chunks
// -> L3 dedups W. Predicted FETCH -> 0.3-0.6GB; gemm -> 400-425us if HBM-bound.

#define MFMA_(Af, Bf, C) __builtin_amdgcn_mfma_f32_16x16x32_bf16(Af, Bf, C, 0, 0, 0)

#define ACCS(F) \
    F(0,0) F(0,1) F(0,2) F(0,3) F(1,0) F(1,1) F(1,2) F(1,3) \
    F(2,0) F(2,1) F(2,2) F(2,3) F(3,0) F(3,1) F(3,2) F(3,3)

#define READF(KH) \
    a0 = ldA(0, KH); a1 = ldA(1, KH); a2 = ldA(2, KH); a3 = ldA(3, KH); \
    b0 = ldB(0, KH); b1 = ldB(1, KH); b2 = ldB(2, KH); b3 = ldB(3, KH);

#define MFMA_ALL \
    c00 = MFMA_(a0, b0, c00); c01 = MFMA_(a0, b1, c01); \
    c02 = MFMA_(a0, b2, c02); c03 = MFMA_(a0, b3, c03); \
    c10 = MFMA_(a1, b0, c10); c11 = MFMA_(a1, b1, c11); \
    c12 = MFMA_(a1, b2, c12); c13 = MFMA_(a1, b3, c13); \
    c20 = MFMA_(a2, b0, c20); c21 = MFMA_(a2, b1, c21); \
    c22 = MFMA_(a2, b2, c22); c23 = MFMA_(a2, b3, c23); \
    c30 = MFMA_(a3, b0, c30); c31 = MFMA_(a3, b1, c31); \
    c32 = MFMA_(a3, b2, c32); c33 = MFMA_(a3, b3, c33);

__global__ __launch_bounds__(256, 3) void gemm_fused(
    const __bf16* __restrict__ A,     // [8192][2048]
    const __bf16* __restrict__ W,     // [10240][2048]
    const float* __restrict__ bias,   // [10240]
    float* __restrict__ out,
    __bf16* __restrict__ ggi, __bf16* __restrict__ ggf,
    __bf16* __restrict__ ggib, __bf16* __restrict__ ggfb,
    __bf16* __restrict__ gpc) {
    __shared__ __bf16 As[8192];   // [128][64], chunk-swizzled
    __shared__ __bf16 Bs[8192];   // [128][64], chunk-swizzled

    // 2D-chunked per-XCD mapping: tm band of 8 per XCD; tn in 8 chunks of 10.
    const int bid = blockIdx.x;
    const int xcd = bid & 7;
    const int j   = bid >> 3;            // 0..639 within this XCD
    const int ch  = j / 80;              // 0..7   tn chunk (lockstep across XCDs)
    const int jj  = j % 80;              // 0..79  inside 8tm x 10tn sub-rectangle
    const int tm  = (xcd << 3) + (jj & 7);   // xcd*8 .. xcd*8+7 (A band, L2-resident)
    const int tn  = ch * 10 + (jj >> 3);     // 0..79

    const int t     = threadIdx.x;
    const int lane  = t & 63;
    const int w     = t >> 6;          // 0..3
    const int wmOff = (w >> 1) << 6;   // 0 or 64
    const int wnOff = (w & 1) << 6;    // 0 or 64
    const int lr    = lane & 15;
    const int kg    = lane >> 4;       // 0..3

    const int64_t Arow0 = (int64_t)tm * 128;
    const int64_t Wrow0 = (int64_t)tn * 128;

#define DA(M, N) f32x4 c##M##N = {0.f, 0.f, 0.f, 0.f};
    ACCS(DA)
#undef DA
    bf16x8 a0, a1, a2, a3, b0, b1, b2, b3;

    // staging: thread t covers LDS row (t>>3), physical chunk (t&7); it must LOAD the
    // inverse-swizzled global chunk (t&7)^((t>>3)&7). LDS dest linear: base + t*16B.
    const int srcChunk = ((t & 7) ^ ((t >> 3) & 7)) << 3;  // elements
    const __bf16* aSrc = A + (Arow0 + (t >> 3)) * (int64_t)K_DIM + srcChunk;
    const __bf16* bSrc = W + (Wrow0 + (t >> 3)) * (int64_t)K_DIM + srcChunk;
    __bf16* ldsA = As + t * 8;
    __bf16* ldsB = Bs + t * 8;

    // swizzled fragment-read bases: logical chunk c=kg+4*kh of row r lives at byte
    // r*128 + ((c^(r&7))<<4). kh=1 flips chunk bit2 -> base with ca^4. m: +2048B.
    const int xr  = lr & 7;
    const int ca  = kg ^ xr;                 // logical chunk for kh=0
    const char* aRd0 = reinterpret_cast<const char*>(As) + (wmOff + lr) * 128 + (ca << 4);
    const char* aRd1 = reinterpret_cast<const char*>(As) + (wmOff + lr) * 128 + ((ca ^ 4) << 4);
    const char* bRd0 = reinterpret_cast<const char*>(Bs) + (wnOff + lr) * 128 + (ca << 4);
    const char* bRd1 = reinterpret_cast<const char*>(Bs) + (wnOff + lr) * 128 + ((ca ^ 4) << 4);

    auto ldA = [&](int m, int kh) {
        return *reinterpret_cast<const bf16x8*>((kh ? aRd1 : aRd0) + m * 2048);
    };
    auto ldB = [&](int n, int kh) {
        return *reinterpret_cast<const bf16x8*>((kh ? bRd1 : bRd0) + n * 2048);
    };

#pragma unroll 1
    for (int kt = 0; kt < 32; ++kt) {
        const int k0 = kt << 6;
        __syncthreads();   // everyone done reading previous tile
        gload_lds16(aSrc + 0 * (32 * K_DIM) + k0, ldsA + 0 * 2048);
        gload_lds16(aSrc + 1 * (32 * K_DIM) + k0, ldsA + 1 * 2048);
        gload_lds16(aSrc + 2 * (32 * K_DIM) + k0, ldsA + 2 * 2048);
        gload_lds16(aSrc + 3 * (32 * K_DIM) + k0, ldsA + 3 * 2048);
        gload_lds16(bSrc + 0 * (32 * K_DIM) + k0, ldsB + 0 * 2048);
        gload_lds16(bSrc + 1 * (32 * K_DIM) + k0, ldsB + 1 * 2048);
        gload_lds16(bSrc + 2 * (32 * K_DIM) + k0, ldsB + 2 * 2048);
        gload_lds16(bSrc + 3 * (32 * K_DIM) + k0, ldsB + 3 * 2048);
        __syncthreads();   // compiler drains vmcnt before barrier: tile landed
        READF(0)
        MFMA_ALL
        READF(1)
        MFMA_ALL
    }
    __syncthreads();

    // ---- fused epilogue (bias folded here) ----
    const float bv0 = bias[Wrow0 + wnOff + 0 * 16 + lr];
    const float bv1 = bias[Wrow0 + wnOff + 1 * 16 + lr];
    const float bv2 = bias[Wrow0 + wnOff + 2 * 16 + lr];
    const float bv3 = bias[Wrow0 + wnOff + 3 * 16 + lr];

    const int     blk = tn >> 3;  // 128-col tile fully inside one 1024-col gate block
    const int     lg  = lane >> 4;
    const int64_t BH  = (int64_t)B_DIM * H_DIM;

    auto epi = [&](int m, int n, f32x4 a, float bv) {
        const int64_t rowb = Arow0 + wmOff + m * 16 + lg * 4;
        const int     colo = wnOff + n * 16 + lr;
        if (blk == 2) {  // go -> fp32 output (never re-read: nontemporal)
            float* dst = out + 6 * BH + (Wrow0 - 2 * (int64_t)H_DIM) + colo;
#pragma unroll
            for (int r = 0; r < 4; ++r)
                __builtin_nontemporal_store(sigmoid_f(a[r] + bv), dst + (rowb + r) * H_DIM);
        } else if (blk >= 6) {  // decay -> fp32 output ([B,4H] row-major, never re-read)
            float* dst = out + 2 * BH + (Wrow0 - 6 * (int64_t)H_DIM) + colo;
#pragma unroll
            for (int r = 0; r < 4; ++r)
                __builtin_nontemporal_store(softplus_f(a[r] + bv), dst + (rowb + r) * 4 * H_DIM);
        } else {  // gate -> bf16 workspace (re-read by combine: keep cacheable)
            __bf16* gp = (blk == 0) ? ggi : (blk == 1) ? ggf
                       : (blk == 3) ? ggib : (blk == 4) ? ggfb : gpc;
            __bf16* dst = gp + (int)(Wrow0 & 1023) + colo;
            if (blk == 5) {
#pragma unroll
                for (int r = 0; r < 4; ++r) dst[(rowb + r) * H_DIM] = (__bf16)tanh_f(a[r] + bv);
            } else {
#pragma unroll
                for (int r = 0; r < 4; ++r) dst[(rowb + r) * H_DIM] = (__bf16)sigmoid_f(a[r] + bv);
            }
        }
    };
#define EPI(M, N) epi(M, N, c##M##N, bv##N);
    ACCS(EPI)
#undef EPI
}

// ---------------- combine (cell outputs never re-read: nontemporal stores) ----------------

__global__ void combine_kernel(const __bf16* __restrict__ ggi, const __bf16* __restrict__ ggf,
                               const __bf16* __restrict__ ggib, const __bf16* __restrict__ ggfb,
                               const __bf16* __restrict__ gpc, const float* __restrict__ cp,
                               const float* __restrict__ cbp, float* __restrict__ out) {
    const int64_t BH    = (int64_t)B_DIM * H_DIM;
    const int64_t total = BH / 8;
    for (int64_t i = (int64_t)blockIdx.x * blockDim.x + threadIdx.x; i < total;
         i += (int64_t)gridDim.x * blockDim.x) {
        int64_t e = i << 3;
        bf16x8 vgi  = *reinterpret_cast<const bf16x8*>(ggi + e);
        bf16x8 vgf  = *reinterpret_cast<const bf16x8*>(ggf + e);
        bf16x8 vgib = *reinterpret_cast<const bf16x8*>(ggib + e);
        bf16x8 vgfb = *reinterpret_cast<const bf16x8*>(ggfb + e);
        bf16x8 vpc  = *reinterpret_cast<const bf16x8*>(gpc + e);
        float4 c0  = *reinterpret_cast<const float4*>(cp + e);
        float4 c1  = *reinterpret_cast<const float4*>(cp + e + 4);
        float4 cb0 = *reinterpret_cast<const float4*>(cbp + e);
        float4 cb1 = *reinterpret_cast<const float4*>(cbp + e + 4);
        float cpa[8] = {c0.x, c0.y, c0.z, c0.w, c1.x, c1.y, c1.z, c1.w};
        float cba[8] = {cb0.x, cb0.y, cb0.z, cb0.w, cb1.x, cb1.y, cb1.z, cb1.w};
        float ci[8], cbi[8];
#pragma unroll
        for (int j = 0; j < 8; ++j) {
            float pc = (float)vpc[j];
            ci[j]  = (float)vgf[j]  * cpa[j] + (float)vgi[j]  * pc;
            cbi[j] = (float)vgfb[j] * cba[j] + (float)vgib[j] * pc;
        }
        f32x4 ci0 = {ci[0], ci[1], ci[2], ci[3]};
        f32x4 ci1 = {ci[4], ci[5], ci[6], ci[7]};
        f32x4 cb0v = {cbi[0], cbi[1], cbi[2], cbi[3]};
        f32x4 cb1v = {cbi[4], cbi[5], cbi[6], cbi[7]};
        f32x4* o0 = reinterpret_cast<f32x4*>(out + e);
        __builtin_nontemporal_store(ci0, &o0[0]);
        __builtin_nontemporal_store(ci1, &o0[1]);
        f32x4* o1 = reinterpret_cast<f32x4*>(out + BH + e);
        __builtin_nontemporal_store(cb0v, &o1[0]);
        __builtin_nontemporal_store(cb1v, &o1[1]);
    }
}

// ---------------- launch ----------------

extern "C" void kernel_launch(void* const* d_in, const int* in_sizes, int n_in,
                              void* d_out, int out_size, void* d_ws, size_t ws_size,
                              hipStream_t stream) {
    const float* x   = (const float*)d_in[0];
    const float* h   = (const float*)d_in[1];
    const float* cp  = (const float*)d_in[2];
    const float* cbp = (const float*)d_in[3];
    const float* Wi  = (const float*)d_in[4];
    const float* bi  = (const float*)d_in[5];
    const float* Wf  = (const float*)d_in[6];
    const float* bfo = (const float*)d_in[7];
    const float* Wo  = (const float*)d_in[8];
    const float* bo  = (const float*)d_in[9];
    const float* Wib = (const float*)d_in[10];
    const float* bib = (const float*)d_in[11];
    const float* Wfb = (const float*)d_in[12];
    const float* bfb = (const float*)d_in[13];
    const float* Wpc = (const float*)d_in[14];
    const float* bpc = (const float*)d_in[15];
    const float* Wd  = (const float*)d_in[16];
    const float* bd  = (const float*)d_in[17];
    float* out = (float*)d_out;

    char* ws = (char*)d_ws;
    __bf16* xh   = (__bf16*)ws;
    __bf16* Wb   = (__bf16*)(ws + 33554432);
    float*  bias = (float*)(ws + 75497472);
    __bf16* ggi  = (__bf16*)(ws + 75538432);
    const size_t BH = (size_t)B_DIM * H_DIM;
    __bf16* ggf  = ggi + BH;
    __bf16* ggib = ggf + BH;
    __bf16* ggfb = ggib + BH;
    __bf16* gpc  = ggfb + BH;

    pack_xh_kernel<<<2048, 256, 0, stream>>>(x, h, xh);
    pack_W_kernel<<<2048, 256, 0, stream>>>(Wi, Wf, Wo, Wib, Wfb, Wpc, Wd, Wb);
    pack_bias_kernel<<<40, 256, 0, stream>>>(bi, bfo, bo, bib, bfb, bpc, bd, bias);

    const int grid = (B_DIM / 128) * (N_DIM / 128);  // 5120
    gemm_fused<<<grid, 256, 0, stream>>>(xh, Wb, bias, out, ggi, ggf, ggib, ggfb, gpc);

    combine_kernel<<<4096, 256, 0, stream>>>(ggi, ggf, ggib, ggfb, gpc, cp, cbp, out);
}